// Round 13
// baseline (276.260 us; speedup 1.0000x reference)
//
#include <hip/hip_runtime.h>

#define D_FEAT 64
constexpr float SLOPE = 0.01f;
constexpr float EPS_N = 1e-6f;
constexpr int SCAN_CHUNK = 2048;   // elements per scan block (256 thr x 8)
constexpr int LDT = 66;            // LDS row stride (pad 64 -> 66)
constexpr int CHUNK_E = 4096;      // edges per binning block
constexpr int BUCKET_SHIFT = 8;    // 256 nodes per bucket
constexpr int BUCKET_NODES = 256;
constexpr int NB_MAX = 512;        // max buckets supported by LDS hist
constexpr int NSPLIT = 8;          // blocks per graph for norm partial reduce

__device__ __forceinline__ float lrelu(float v) { return v >= 0.f ? v : SLOPE * v; }

// bf16 round-to-nearest-even, hand-rolled (no API ambiguity)
__device__ __forceinline__ unsigned short f2bf(float f) {
    union { float f; unsigned u; } v; v.f = f;
    unsigned r = v.u + 0x7FFF + ((v.u >> 16) & 1);
    return (unsigned short)(r >> 16);
}
__device__ __forceinline__ float bf2f(unsigned short b) {
    union { unsigned u; float f; } v; v.u = (unsigned)b << 16;
    return v.f;
}

// ---------------------------------------------------------------------------
// FUSED kernel: blocks [0, nsort) run bucket_sort (CSR finalize);
// blocks [nsort, nsort+nmlp) run the 3-stage MLP (R11 GEMM, bf16 h output).
// bsort (~20us) hides completely under mlp (~64us); both must precede gather.
// LDS: single 50688B buffer, aliased by both paths.
// ---------------------------------------------------------------------------
__global__ __launch_bounds__(256, 3) void fused_sort_mlp_kernel(
    // bucket_sort args
    const int* __restrict__ bh, const int* __restrict__ partials,
    const int2* __restrict__ rec, int2* __restrict__ rec2,
    int* __restrict__ row_start, int n_edges, int nb, int nch,
    // mlp args
    const float* __restrict__ x, const float* __restrict__ states,
    const float* __restrict__ Ws, const float* __restrict__ W1,
    const float* __restrict__ W2, unsigned short* __restrict__ h,
    int n_nodes, int nsort)
{
    __shared__ float smem[D_FEAT * LDT * 3];   // 50688 B

    const int t = threadIdx.x;

    if ((int)blockIdx.x < nsort) {
        // ================= bucket_sort path =================
        int* cnt = (int*)smem;
        int* s   = cnt + BUCKET_NODES;
        int* pos = s + BUCKET_NODES;

        const int b = blockIdx.x;
        const int iS = b * nch;
        const int S = bh[iS] + partials[iS / SCAN_CHUNK];
        int E = n_edges;
        if (b + 1 < nb) {
            int iE = (b + 1) * nch;
            E = bh[iE] + partials[iE / SCAN_CHUNK];
        }

        cnt[t] = 0;
        __syncthreads();
        for (int i = S + t; i < E; i += 256)
            atomicAdd(&cnt[rec[i].x >> 20], 1);
        __syncthreads();

        int my = cnt[t];
        s[t] = my;
        __syncthreads();
        for (int off = 1; off < 256; off <<= 1) {
            int y = (t >= off) ? s[t - off] : 0;
            __syncthreads();
            s[t] += y;
            __syncthreads();
        }
        int excl = s[t] - my;
        pos[t] = S + excl;
        const int node = (b << BUCKET_SHIFT) + t;
        if (node < n_nodes) row_start[node] = S + excl;
        if (b == nb - 1 && t == 0) row_start[n_nodes] = n_edges;
        __syncthreads();

        for (int i = S + t; i < E; i += 256) {
            int2 r = rec[i];
            int p = atomicAdd(&pos[r.x >> 20], 1);
            rec2[p] = r;
        }
        return;
    }

    // ================= MLP path (R11 structure, bf16 output) =================
    float* S_t = smem;
    float* H_t = smem + D_FEAT * LDT;
    float* W_t = smem + 2 * D_FEAT * LDT;

    const int tn4 = (t & 15) * 4;
    const int tc4 = (t >> 4) * 4;
    const int nbase = ((int)blockIdx.x - nsort) * 64;

#define STAGE_W(Wp)                                                          \
    {                                                                        \
        const int wrow = t >> 2;                                             \
        _Pragma("unroll")                                                    \
        for (int s2 = (t & 3); s2 < 16; s2 += 4) {                           \
            float4 wv = *reinterpret_cast<const float4*>((Wp) + wrow * 64 + s2 * 4); \
            W_t[(s2 * 4 + 0) * LDT + wrow] = wv.x;                           \
            W_t[(s2 * 4 + 1) * LDT + wrow] = wv.y;                           \
            W_t[(s2 * 4 + 2) * LDT + wrow] = wv.z;                           \
            W_t[(s2 * 4 + 3) * LDT + wrow] = wv.w;                           \
        }                                                                    \
    }

#define GEMM_LOOP(SRC)                                                       \
    _Pragma("unroll 8")                                                      \
    for (int k = 0; k < D_FEAT; ++k) {                                       \
        float4 a = *reinterpret_cast<const float4*>(&SRC[k * LDT + tn4]);    \
        float4 b = *reinterpret_cast<const float4*>(&W_t[k * LDT + tc4]);    \
        const float av[4] = {a.x, a.y, a.z, a.w};                            \
        const float bv[4] = {b.x, b.y, b.z, b.w};                            \
        _Pragma("unroll")                                                    \
        for (int i = 0; i < 4; ++i)                                          \
            _Pragma("unroll")                                                \
            for (int j = 0; j < 4; ++j)                                      \
                acc[i][j] += av[i] * bv[j];                                  \
    }

    STAGE_W(Ws);
    {
        const int r = t >> 4, kg = t & 15;
        #pragma unroll
        for (int i = 0; i < 4; ++i) {
            int nloc = r + i * 16;
            int node = nbase + nloc;
            float4 sv = make_float4(0.f, 0.f, 0.f, 0.f);
            if (node < n_nodes)
                sv = *reinterpret_cast<const float4*>(states + (size_t)node * D_FEAT + kg * 4);
            S_t[(kg * 4 + 0) * LDT + nloc] = sv.x;
            S_t[(kg * 4 + 1) * LDT + nloc] = sv.y;
            S_t[(kg * 4 + 2) * LDT + nloc] = sv.z;
            S_t[(kg * 4 + 3) * LDT + nloc] = sv.w;
        }
    }
    __syncthreads();

    float acc[4][4];

    // ---- stage 1: h2 = lrelu(x + states @ Ws^T) ----
    #pragma unroll
    for (int i = 0; i < 4; ++i) {
        int node = nbase + tn4 + i;
        if (node < n_nodes) {
            float4 xv = *reinterpret_cast<const float4*>(x + (size_t)node * D_FEAT + tc4);
            acc[i][0] = xv.x; acc[i][1] = xv.y; acc[i][2] = xv.z; acc[i][3] = xv.w;
        } else {
            acc[i][0] = acc[i][1] = acc[i][2] = acc[i][3] = 0.f;
        }
    }
    GEMM_LOOP(S_t);
    #pragma unroll
    for (int j = 0; j < 4; ++j) {
        float4 col = make_float4(lrelu(acc[0][j]), lrelu(acc[1][j]),
                                 lrelu(acc[2][j]), lrelu(acc[3][j]));
        *reinterpret_cast<float4*>(&H_t[(tc4 + j) * LDT + tn4]) = col;
    }
    __syncthreads();

    STAGE_W(W1);
    __syncthreads();

    // ---- stage 2: h3 = lrelu(h2 @ W1^T) ----
    #pragma unroll
    for (int i = 0; i < 4; ++i)
        #pragma unroll
        for (int j = 0; j < 4; ++j)
            acc[i][j] = 0.f;
    GEMM_LOOP(H_t);
    #pragma unroll
    for (int j = 0; j < 4; ++j) {
        float4 col = make_float4(lrelu(acc[0][j]), lrelu(acc[1][j]),
                                 lrelu(acc[2][j]), lrelu(acc[3][j]));
        *reinterpret_cast<float4*>(&S_t[(tc4 + j) * LDT + tn4]) = col;
    }
    __syncthreads();

    STAGE_W(W2);
    __syncthreads();

    // ---- stage 3: h = h3 @ W2^T, store bf16 ----
    #pragma unroll
    for (int i = 0; i < 4; ++i)
        #pragma unroll
        for (int j = 0; j < 4; ++j)
            acc[i][j] = 0.f;
    GEMM_LOOP(S_t);
    #pragma unroll
    for (int i = 0; i < 4; ++i) {
        int node = nbase + tn4 + i;
        if (node < n_nodes) {
            ushort4 o = make_ushort4(f2bf(acc[i][0]), f2bf(acc[i][1]),
                                     f2bf(acc[i][2]), f2bf(acc[i][3]));
            *reinterpret_cast<ushort4*>(h + (size_t)node * D_FEAT + tc4) = o;
        }
    }
#undef STAGE_W
#undef GEMM_LOOP
}

// ---------------------------------------------------------------------------
// Pass A: per-chunk bucket histogram (bucket = dst >> BUCKET_SHIFT).
// ---------------------------------------------------------------------------
__global__ __launch_bounds__(256) void binhist_kernel(
    const int* __restrict__ eidx, int* __restrict__ bh,
    int n_edges, int nb, int nch)
{
    __shared__ int hist[NB_MAX];
    const int c = blockIdx.x, t = threadIdx.x;
    for (int i = t; i < nb; i += 256) hist[i] = 0;
    __syncthreads();
    const int base = c * CHUNK_E;
    #pragma unroll 4
    for (int k = 0; k < CHUNK_E / 256; ++k) {
        int e = base + k * 256 + t;
        if (e < n_edges) atomicAdd(&hist[eidx[e] >> BUCKET_SHIFT], 1);
    }
    __syncthreads();
    for (int i = t; i < nb; i += 256) bh[i * nch + c] = hist[i];
}

// ---------------------------------------------------------------------------
// Scan: local exclusive per 2048-chunk (scan1) + partials scan (scan2).
// ---------------------------------------------------------------------------
__global__ __launch_bounds__(256) void scan1_kernel(
    const int* __restrict__ in, int* __restrict__ out,
    int* __restrict__ partials, int n)
{
    __shared__ int s[256];
    const int b = blockIdx.x, t = threadIdx.x;
    const int base = b * SCAN_CHUNK + t * 8;
    int v[8]; int sum = 0;
    #pragma unroll
    for (int i = 0; i < 8; ++i) {
        v[i] = (base + i < n) ? in[base + i] : 0;
        sum += v[i];
    }
    s[t] = sum;
    __syncthreads();
    for (int off = 1; off < 256; off <<= 1) {
        int y = (t >= off) ? s[t - off] : 0;
        __syncthreads();
        s[t] += y;
        __syncthreads();
    }
    int excl = s[t] - sum;
    #pragma unroll
    for (int i = 0; i < 8; ++i) {
        if (base + i < n) out[base + i] = excl;
        excl += v[i];
    }
    if (t == 255) partials[b] = s[255];
}

__global__ __launch_bounds__(256) void scan2_kernel(int* partials, int nchunks)
{
    __shared__ int s[256];
    const int t = threadIdx.x;
    int v = (t < nchunks) ? partials[t] : 0;
    s[t] = v;
    __syncthreads();
    for (int off = 1; off < 256; off <<= 1) {
        int y = (t >= off) ? s[t - off] : 0;
        __syncthreads();
        s[t] += y;
        __syncthreads();
    }
    if (t < nchunks) partials[t] = s[t] - v;      // exclusive
}

// ---------------------------------------------------------------------------
// Pass B: binned scatter into per-(bucket,chunk) contiguous runs.
// rec.x = (dstLocal << 20) | src,  rec.y = w bits.
// ---------------------------------------------------------------------------
__global__ __launch_bounds__(256) void binscatter_kernel(
    const int* __restrict__ eidx, const float* __restrict__ w,
    const int* __restrict__ bh, const int* __restrict__ partials,
    int2* __restrict__ rec, int n_edges, int nb, int nch)
{
    __shared__ int cur[NB_MAX];
    const int c = blockIdx.x, t = threadIdx.x;
    for (int i = t; i < nb; i += 256) {
        int idx = i * nch + c;
        cur[i] = bh[idx] + partials[idx / SCAN_CHUNK];
    }
    __syncthreads();
    const int base = c * CHUNK_E;
    #pragma unroll 4
    for (int k = 0; k < CHUNK_E / 256; ++k) {
        int e = base + k * 256 + t;
        if (e < n_edges) {
            int dst = eidx[e];
            int src = eidx[n_edges + e];
            float wv = w[e];
            int b = dst >> BUCKET_SHIFT;
            int dl = dst & (BUCKET_NODES - 1);
            int pos = atomicAdd(&cur[b], 1);
            rec[pos] = make_int2((dl << 20) | src, __float_as_int(wv));
        }
    }
}

// ---------------------------------------------------------------------------
// Pass C: atomic-free gather. One wave per destination node, lane = channel.
// h is bf16 -> gather traffic halves (~307 -> ~154 MB).
// ---------------------------------------------------------------------------
__global__ __launch_bounds__(256, 8) void node_gather_kernel(
    const int* __restrict__ row_start, const int2* __restrict__ rec2,
    const unsigned short* __restrict__ h, float* __restrict__ agg, int n_nodes)
{
    const int node = blockIdx.x * 4 + (threadIdx.x >> 6);
    const int lane = threadIdx.x & 63;
    if (node >= n_nodes) return;

    const int start = row_start[node];
    const int end   = row_start[node + 1];

    float a0 = 0.f, a1 = 0.f, a2 = 0.f, a3 = 0.f;
    int i = start;
    for (; i + 4 <= end; i += 4) {
        int2 r0 = rec2[i];
        int2 r1 = rec2[i + 1];
        int2 r2 = rec2[i + 2];
        int2 r3 = rec2[i + 3];
        float h0 = bf2f(h[(size_t)(r0.x & 0xFFFFF) * D_FEAT + lane]);
        float h1 = bf2f(h[(size_t)(r1.x & 0xFFFFF) * D_FEAT + lane]);
        float h2 = bf2f(h[(size_t)(r2.x & 0xFFFFF) * D_FEAT + lane]);
        float h3 = bf2f(h[(size_t)(r3.x & 0xFFFFF) * D_FEAT + lane]);
        a0 += __int_as_float(r0.y) * h0;
        a1 += __int_as_float(r1.y) * h1;
        a2 += __int_as_float(r2.y) * h2;
        a3 += __int_as_float(r3.y) * h3;
    }
    for (; i < end; ++i) {
        int2 r = rec2[i];
        a0 += __int_as_float(r.y) * bf2f(h[(size_t)(r.x & 0xFFFFF) * D_FEAT + lane]);
    }
    agg[(size_t)node * D_FEAT + lane] = (a0 + a1) + (a2 + a3);
}

// ---------------------------------------------------------------------------
// Fallback scatter (atomics) if workspace too small / shape unsupported
// ---------------------------------------------------------------------------
__global__ __launch_bounds__(256) void scatter_atomic_kernel(
    const int* __restrict__ eidx, const float* __restrict__ w,
    const unsigned short* __restrict__ h, float* __restrict__ agg, int n_edges)
{
    long long t = (long long)blockIdx.x * blockDim.x + threadIdx.x;
    int e = (int)(t >> 4);
    if (e >= n_edges) return;
    int c = ((int)t & 15) * 4;
    int dst = eidx[e];
    int src = eidx[n_edges + e];
    float wv = w[e];
    const unsigned short* hp = h + (size_t)src * D_FEAT + c;
    float* p = agg + (size_t)dst * D_FEAT + c;
    unsafeAtomicAdd(p + 0, wv * bf2f(hp[0]));
    unsafeAtomicAdd(p + 1, wv * bf2f(hp[1]));
    unsafeAtomicAdd(p + 2, wv * bf2f(hp[2]));
    unsafeAtomicAdd(p + 3, wv * bf2f(hp[3]));
}

// ---------------------------------------------------------------------------
// GraphNorm, parallelized: partial reduce -> finalize -> apply.
// ---------------------------------------------------------------------------
__global__ __launch_bounds__(256) void norm_part_kernel(
    const float* __restrict__ io, float* __restrict__ part, int npg)
{
    const int g = blockIdx.x / NSPLIT;
    const int s = blockIdx.x % NSPLIT;
    const int t = threadIdx.x;
    const int j = t & 63;
    const int r = t >> 6;
    const int chunk = (npg + NSPLIT - 1) / NSPLIT;
    const int n0 = s * chunk;
    const int n1 = min(npg, n0 + chunk);
    const size_t base = (size_t)g * npg * D_FEAT;

    float sum = 0.f, sq = 0.f;
    for (int n = n0 + r; n < n1; n += 4) {
        float v = io[base + (size_t)n * D_FEAT + j];
        sum += v; sq += v * v;
    }
    __shared__ float s_red[2][4][64];
    s_red[0][r][j] = sum;
    s_red[1][r][j] = sq;
    __syncthreads();
    if (r == 0) {
        float S = s_red[0][0][j] + s_red[0][1][j] + s_red[0][2][j] + s_red[0][3][j];
        float Q = s_red[1][0][j] + s_red[1][1][j] + s_red[1][2][j] + s_red[1][3][j];
        part[(size_t)blockIdx.x * 128 + j]      = S;
        part[(size_t)blockIdx.x * 128 + 64 + j] = Q;
    }
}

__global__ __launch_bounds__(64) void norm_fin_kernel(
    const float* __restrict__ part, float* __restrict__ musc,
    const float* __restrict__ gamma, int npg)
{
    const int g = blockIdx.x;
    const int j = threadIdx.x;
    float S = 0.f, Q = 0.f;
    #pragma unroll
    for (int s = 0; s < NSPLIT; ++s) {
        S += part[(size_t)(g * NSPLIT + s) * 128 + j];
        Q += part[(size_t)(g * NSPLIT + s) * 128 + 64 + j];
    }
    float cnt = (float)npg;
    float mu = S / cnt;
    float var = (Q - cnt * mu * mu) / fmaxf(cnt - 1.f, 1.f);
    var = fmaxf(var, 0.f);
    musc[g * 128 + j]      = mu;
    musc[g * 128 + 64 + j] = gamma[j] / (sqrtf(var) + EPS_N);
}

__global__ __launch_bounds__(256) void norm_apply_kernel(
    float* __restrict__ io, const float* __restrict__ musc,
    const float* __restrict__ beta, int n_nodes, int npg)
{
    const int nf4 = n_nodes * 16;   // float4 count
    for (int i4 = blockIdx.x * blockDim.x + threadIdx.x; i4 < nf4;
         i4 += gridDim.x * blockDim.x) {
        int node = i4 >> 4;
        int j0 = (i4 & 15) * 4;
        int g = node / npg;
        float4 v  = *reinterpret_cast<float4*>(io + (size_t)i4 * 4);
        float4 mu = *reinterpret_cast<const float4*>(musc + g * 128 + j0);
        float4 sc = *reinterpret_cast<const float4*>(musc + g * 128 + 64 + j0);
        float4 be = *reinterpret_cast<const float4*>(beta + j0);
        v.x = (v.x - mu.x) * sc.x + be.x;
        v.y = (v.y - mu.y) * sc.y + be.y;
        v.z = (v.z - mu.z) * sc.z + be.z;
        v.w = (v.w - mu.w) * sc.w + be.w;
        *reinterpret_cast<float4*>(io + (size_t)i4 * 4) = v;
    }
}

extern "C" void kernel_launch(void* const* d_in, const int* in_sizes, int n_in,
                              void* d_out, int out_size, void* d_ws, size_t ws_size,
                              hipStream_t stream)
{
    const float* x      = (const float*)d_in[0];
    const float* states = (const float*)d_in[1];
    const int*   eidx   = (const int*)d_in[2];
    const float* w      = (const float*)d_in[3];
    const float* Ws     = (const float*)d_in[6];
    const float* W1     = (const float*)d_in[7];
    const float* W2     = (const float*)d_in[8];
    const float* gamma  = (const float*)d_in[9];
    const float* beta   = (const float*)d_in[10];

    const int n_nodes  = in_sizes[0] / D_FEAT;
    const int n_edges  = in_sizes[3];
    const int n_graphs = in_sizes[5];
    const int npg      = n_nodes / n_graphs;

    const int nb  = (n_nodes + BUCKET_NODES - 1) / BUCKET_NODES;  // 391
    const int nch = (n_edges + CHUNK_E - 1) / CHUNK_E;            // 293
    const int nscan = nb * nch;
    const int nmlp = (n_nodes + 63) / 64;                         // 1563

    // workspace layout: h(bf16) | rec | rec2 | bh | partials | row_start
    char* ws = (char*)d_ws;
    size_t hBytes    = ((size_t)n_nodes * D_FEAT * sizeof(unsigned short) + 15) & ~15ULL; // 12.8 MB
    size_t recBytes  = (size_t)n_edges * sizeof(int2);            // 9.6 MB
    size_t bhBytes   = (size_t)nscan * sizeof(int);
    size_t partBytes = 256 * sizeof(int);
    size_t rsBytes   = (size_t)(n_nodes + 1) * sizeof(int);
    size_t need = hBytes + 2 * recBytes + bhBytes + partBytes + rsBytes;

    unsigned short* h = (unsigned short*)ws;
    float* agg = (float*)d_out;

    // norm scratch aliases the rec region (rec dead after fused sort+mlp)
    float* nrm_part = (float*)(ws + hBytes);
    float* nrm_musc = nrm_part + (size_t)n_graphs * NSPLIT * 128;

    const bool ok = (ws_size >= need) && (nb <= NB_MAX) && (n_nodes < (1 << 20));
    if (ok) {
        int2* rec      = (int2*)(ws + hBytes);
        int2* rec2     = (int2*)(ws + hBytes + recBytes);
        int*  bh       = (int*)(ws + hBytes + 2 * recBytes);
        int*  partials = (int*)(ws + hBytes + 2 * recBytes + bhBytes);
        int*  row_start= (int*)(ws + hBytes + 2 * recBytes + bhBytes + partBytes);

        binhist_kernel<<<nch, 256, 0, stream>>>(eidx, bh, n_edges, nb, nch);

        int nchunks = (nscan + SCAN_CHUNK - 1) / SCAN_CHUNK;
        scan1_kernel<<<nchunks, 256, 0, stream>>>(bh, bh, partials, nscan);  // in-place
        scan2_kernel<<<1, 256, 0, stream>>>(partials, nchunks);

        binscatter_kernel<<<nch, 256, 0, stream>>>(eidx, w, bh, partials, rec,
                                                   n_edges, nb, nch);

        // bucket_sort (391 blocks) hidden under mlp (1563 blocks)
        fused_sort_mlp_kernel<<<nb + nmlp, 256, 0, stream>>>(
            bh, partials, rec, rec2, row_start, n_edges, nb, nch,
            x, states, Ws, W1, W2, h, n_nodes, nb);

        node_gather_kernel<<<(n_nodes + 3) / 4, 256, 0, stream>>>(row_start, rec2, h,
                                                                  agg, n_nodes);
    } else {
        // fallback: mlp only (nsort = 0), then atomic scatter
        fused_sort_mlp_kernel<<<nmlp, 256, 0, stream>>>(
            nullptr, nullptr, nullptr, nullptr, nullptr, n_edges, 0, nch,
            x, states, Ws, W1, W2, h, n_nodes, 0);
        hipMemsetAsync(agg, 0, (size_t)n_nodes * D_FEAT * sizeof(float), stream);
        long long sthreads = (long long)n_edges * 16;
        int sblocks = (int)((sthreads + 255) / 256);
        scatter_atomic_kernel<<<sblocks, 256, 0, stream>>>(eidx, w, h, agg, n_edges);
    }

    norm_part_kernel<<<n_graphs * NSPLIT, 256, 0, stream>>>(agg, nrm_part, npg);
    norm_fin_kernel<<<n_graphs, 64, 0, stream>>>(nrm_part, nrm_musc, gamma, npg);
    norm_apply_kernel<<<1024, 256, 0, stream>>>(agg, nrm_musc, beta, n_nodes, npg);
}

// Round 15
// 171.891 us; speedup vs baseline: 1.6072x; 1.6072x over previous
//
#include <hip/hip_runtime.h>

#define D_FEAT 64
constexpr float SLOPE = 0.01f;
constexpr float EPS_N = 1e-6f;
constexpr int SCAN_CHUNK = 2048;   // elements per scan block (256 thr x 8)
constexpr int LDT = 66;            // LDS row stride (pad 64 -> 66)
constexpr int CHUNK_E = 4096;      // edges per binning block
constexpr int BUCKET_SHIFT = 8;    // 256 nodes per bucket
constexpr int BUCKET_NODES = 256;
constexpr int NB_MAX = 512;        // max buckets supported by LDS hist
constexpr int NSPLIT = 8;          // blocks per graph for norm partial reduce

__device__ __forceinline__ float lrelu(float v) { return v >= 0.f ? v : SLOPE * v; }

// bf16 round-to-nearest-even
__device__ __forceinline__ unsigned short f2bf(float f) {
    union { float f; unsigned u; } v; v.f = f;
    unsigned r = v.u + 0x7FFF + ((v.u >> 16) & 1);
    return (unsigned short)(r >> 16);
}
__device__ __forceinline__ float bf2f(unsigned short b) {
    union { unsigned u; float f; } v; v.u = (unsigned)b << 16;
    return v.f;
}

// ---------------------------------------------------------------------------
// MLP: h = (leaky_relu(leaky_relu(x + states@Ws^T) @ W1^T)) @ W2^T
// R11 GEMM structure (68 VGPR, no spill — R10's deeper pipeline spilled,
// R13's fusion with bucket_sort regressed 2.8x; both reverted).
// Output h stored as bf16 (halves gather-stage traffic; absmax 0.016->0.031,
// threshold 0.136).
// ---------------------------------------------------------------------------
__global__ __launch_bounds__(256, 3) void mlp_kernel(
    const float* __restrict__ x, const float* __restrict__ states,
    const float* __restrict__ Ws, const float* __restrict__ W1,
    const float* __restrict__ W2, unsigned short* __restrict__ h, int n_nodes)
{
    __shared__ float S_t[D_FEAT * LDT];
    __shared__ float H_t[D_FEAT * LDT];
    __shared__ float W_t[D_FEAT * LDT];

    const int t   = threadIdx.x;
    const int tn4 = (t & 15) * 4;
    const int tc4 = (t >> 4) * 4;
    const int nb  = blockIdx.x * 64;

#define STAGE_W(Wp)                                                          \
    {                                                                        \
        const int wrow = t >> 2;                                             \
        _Pragma("unroll")                                                    \
        for (int s = (t & 3); s < 16; s += 4) {                              \
            float4 wv = *reinterpret_cast<const float4*>((Wp) + wrow * 64 + s * 4); \
            W_t[(s * 4 + 0) * LDT + wrow] = wv.x;                            \
            W_t[(s * 4 + 1) * LDT + wrow] = wv.y;                            \
            W_t[(s * 4 + 2) * LDT + wrow] = wv.z;                            \
            W_t[(s * 4 + 3) * LDT + wrow] = wv.w;                            \
        }                                                                    \
    }

#define GEMM_LOOP(SRC)                                                       \
    _Pragma("unroll 8")                                                      \
    for (int k = 0; k < D_FEAT; ++k) {                                       \
        float4 a = *reinterpret_cast<const float4*>(&SRC[k * LDT + tn4]);    \
        float4 b = *reinterpret_cast<const float4*>(&W_t[k * LDT + tc4]);    \
        const float av[4] = {a.x, a.y, a.z, a.w};                            \
        const float bv[4] = {b.x, b.y, b.z, b.w};                            \
        _Pragma("unroll")                                                    \
        for (int i = 0; i < 4; ++i)                                          \
            _Pragma("unroll")                                                \
            for (int j = 0; j < 4; ++j)                                      \
                acc[i][j] += av[i] * bv[j];                                  \
    }

    STAGE_W(Ws);
    {
        const int r = t >> 4, kg = t & 15;
        #pragma unroll
        for (int i = 0; i < 4; ++i) {
            int nloc = r + i * 16;
            int node = nb + nloc;
            float4 sv = make_float4(0.f, 0.f, 0.f, 0.f);
            if (node < n_nodes)
                sv = *reinterpret_cast<const float4*>(states + (size_t)node * D_FEAT + kg * 4);
            S_t[(kg * 4 + 0) * LDT + nloc] = sv.x;
            S_t[(kg * 4 + 1) * LDT + nloc] = sv.y;
            S_t[(kg * 4 + 2) * LDT + nloc] = sv.z;
            S_t[(kg * 4 + 3) * LDT + nloc] = sv.w;
        }
    }
    __syncthreads();

    float acc[4][4];

    // ---- stage 1: h2 = lrelu(x + states @ Ws^T) ----
    #pragma unroll
    for (int i = 0; i < 4; ++i) {
        int node = nb + tn4 + i;
        if (node < n_nodes) {
            float4 xv = *reinterpret_cast<const float4*>(x + (size_t)node * D_FEAT + tc4);
            acc[i][0] = xv.x; acc[i][1] = xv.y; acc[i][2] = xv.z; acc[i][3] = xv.w;
        } else {
            acc[i][0] = acc[i][1] = acc[i][2] = acc[i][3] = 0.f;
        }
    }
    GEMM_LOOP(S_t);
    #pragma unroll
    for (int j = 0; j < 4; ++j) {
        float4 col = make_float4(lrelu(acc[0][j]), lrelu(acc[1][j]),
                                 lrelu(acc[2][j]), lrelu(acc[3][j]));
        *reinterpret_cast<float4*>(&H_t[(tc4 + j) * LDT + tn4]) = col;
    }
    __syncthreads();

    STAGE_W(W1);
    __syncthreads();

    // ---- stage 2: h3 = lrelu(h2 @ W1^T) ----
    #pragma unroll
    for (int i = 0; i < 4; ++i)
        #pragma unroll
        for (int j = 0; j < 4; ++j)
            acc[i][j] = 0.f;
    GEMM_LOOP(H_t);
    #pragma unroll
    for (int j = 0; j < 4; ++j) {
        float4 col = make_float4(lrelu(acc[0][j]), lrelu(acc[1][j]),
                                 lrelu(acc[2][j]), lrelu(acc[3][j]));
        *reinterpret_cast<float4*>(&S_t[(tc4 + j) * LDT + tn4]) = col;  // h3 -> S_t
    }
    __syncthreads();

    STAGE_W(W2);
    __syncthreads();

    // ---- stage 3: h = h3 @ W2^T, store bf16 ----
    #pragma unroll
    for (int i = 0; i < 4; ++i)
        #pragma unroll
        for (int j = 0; j < 4; ++j)
            acc[i][j] = 0.f;
    GEMM_LOOP(S_t);
    #pragma unroll
    for (int i = 0; i < 4; ++i) {
        int node = nb + tn4 + i;
        if (node < n_nodes) {
            ushort4 o = make_ushort4(f2bf(acc[i][0]), f2bf(acc[i][1]),
                                     f2bf(acc[i][2]), f2bf(acc[i][3]));
            *reinterpret_cast<ushort4*>(h + (size_t)node * D_FEAT + tc4) = o;
        }
    }
#undef STAGE_W
#undef GEMM_LOOP
}

// ---------------------------------------------------------------------------
// Pass A: per-chunk bucket histogram (bucket = dst >> BUCKET_SHIFT).
// ---------------------------------------------------------------------------
__global__ __launch_bounds__(256) void binhist_kernel(
    const int* __restrict__ eidx, int* __restrict__ bh,
    int n_edges, int nb, int nch)
{
    __shared__ int hist[NB_MAX];
    const int c = blockIdx.x, t = threadIdx.x;
    for (int i = t; i < nb; i += 256) hist[i] = 0;
    __syncthreads();
    const int base = c * CHUNK_E;
    #pragma unroll 4
    for (int k = 0; k < CHUNK_E / 256; ++k) {
        int e = base + k * 256 + t;
        if (e < n_edges) atomicAdd(&hist[eidx[e] >> BUCKET_SHIFT], 1);
    }
    __syncthreads();
    for (int i = t; i < nb; i += 256) bh[i * nch + c] = hist[i];
}

// ---------------------------------------------------------------------------
// Scan: local exclusive per 2048-chunk (scan1) + partials scan (scan2).
// Consumers add partials[idx/SCAN_CHUNK] inline.
// ---------------------------------------------------------------------------
__global__ __launch_bounds__(256) void scan1_kernel(
    const int* __restrict__ in, int* __restrict__ out,
    int* __restrict__ partials, int n)
{
    __shared__ int s[256];
    const int b = blockIdx.x, t = threadIdx.x;
    const int base = b * SCAN_CHUNK + t * 8;
    int v[8]; int sum = 0;
    #pragma unroll
    for (int i = 0; i < 8; ++i) {
        v[i] = (base + i < n) ? in[base + i] : 0;
        sum += v[i];
    }
    s[t] = sum;
    __syncthreads();
    for (int off = 1; off < 256; off <<= 1) {
        int y = (t >= off) ? s[t - off] : 0;
        __syncthreads();
        s[t] += y;
        __syncthreads();
    }
    int excl = s[t] - sum;
    #pragma unroll
    for (int i = 0; i < 8; ++i) {
        if (base + i < n) out[base + i] = excl;
        excl += v[i];
    }
    if (t == 255) partials[b] = s[255];
}

__global__ __launch_bounds__(256) void scan2_kernel(int* partials, int nchunks)
{
    __shared__ int s[256];
    const int t = threadIdx.x;
    int v = (t < nchunks) ? partials[t] : 0;
    s[t] = v;
    __syncthreads();
    for (int off = 1; off < 256; off <<= 1) {
        int y = (t >= off) ? s[t - off] : 0;
        __syncthreads();
        s[t] += y;
        __syncthreads();
    }
    if (t < nchunks) partials[t] = s[t] - v;      // exclusive
}

// ---------------------------------------------------------------------------
// Pass B: binned scatter into per-(bucket,chunk) contiguous runs.
// rec.x = (dstLocal << 20) | src,  rec.y = w bits.
// ---------------------------------------------------------------------------
__global__ __launch_bounds__(256) void binscatter_kernel(
    const int* __restrict__ eidx, const float* __restrict__ w,
    const int* __restrict__ bh, const int* __restrict__ partials,
    int2* __restrict__ rec, int n_edges, int nb, int nch)
{
    __shared__ int cur[NB_MAX];
    const int c = blockIdx.x, t = threadIdx.x;
    for (int i = t; i < nb; i += 256) {
        int idx = i * nch + c;
        cur[i] = bh[idx] + partials[idx / SCAN_CHUNK];
    }
    __syncthreads();
    const int base = c * CHUNK_E;
    #pragma unroll 4
    for (int k = 0; k < CHUNK_E / 256; ++k) {
        int e = base + k * 256 + t;
        if (e < n_edges) {
            int dst = eidx[e];
            int src = eidx[n_edges + e];
            float wv = w[e];
            int b = dst >> BUCKET_SHIFT;
            int dl = dst & (BUCKET_NODES - 1);
            int pos = atomicAdd(&cur[b], 1);
            rec[pos] = make_int2((dl << 20) | src, __float_as_int(wv));
        }
    }
}

// ---------------------------------------------------------------------------
// Pass B2: per-bucket counting sort into per-NODE order + row_start build.
// ---------------------------------------------------------------------------
__global__ __launch_bounds__(256) void bucket_sort_kernel(
    const int* __restrict__ bh, const int* __restrict__ partials,
    const int2* __restrict__ rec, int2* __restrict__ rec2,
    int* __restrict__ row_start, int n_edges, int nb, int nch, int n_nodes)
{
    __shared__ int cnt[BUCKET_NODES];
    __shared__ int s[BUCKET_NODES];
    __shared__ int pos[BUCKET_NODES];

    const int b = blockIdx.x, t = threadIdx.x;
    const int iS = b * nch;
    const int S = bh[iS] + partials[iS / SCAN_CHUNK];
    int E = n_edges;
    if (b + 1 < nb) {
        int iE = (b + 1) * nch;
        E = bh[iE] + partials[iE / SCAN_CHUNK];
    }

    cnt[t] = 0;
    __syncthreads();
    for (int i = S + t; i < E; i += 256)
        atomicAdd(&cnt[rec[i].x >> 20], 1);
    __syncthreads();

    int my = cnt[t];
    s[t] = my;
    __syncthreads();
    for (int off = 1; off < 256; off <<= 1) {
        int y = (t >= off) ? s[t - off] : 0;
        __syncthreads();
        s[t] += y;
        __syncthreads();
    }
    int excl = s[t] - my;
    pos[t] = S + excl;
    const int node = (b << BUCKET_SHIFT) + t;
    if (node < n_nodes) row_start[node] = S + excl;
    if (b == nb - 1 && t == 0) row_start[n_nodes] = n_edges;
    __syncthreads();

    for (int i = S + t; i < E; i += 256) {
        int2 r = rec[i];
        int p = atomicAdd(&pos[r.x >> 20], 1);
        rec2[p] = r;
    }
}

// ---------------------------------------------------------------------------
// Pass C: atomic-free gather. One wave per destination node, lane = channel.
// h is bf16 -> per-edge row read is 128B instead of 256B.
// ---------------------------------------------------------------------------
__global__ __launch_bounds__(256, 8) void node_gather_kernel(
    const int* __restrict__ row_start, const int2* __restrict__ rec2,
    const unsigned short* __restrict__ h, float* __restrict__ agg, int n_nodes)
{
    const int node = blockIdx.x * 4 + (threadIdx.x >> 6);
    const int lane = threadIdx.x & 63;
    if (node >= n_nodes) return;

    const int start = row_start[node];
    const int end   = row_start[node + 1];

    float a0 = 0.f, a1 = 0.f, a2 = 0.f, a3 = 0.f;
    int i = start;
    for (; i + 4 <= end; i += 4) {
        int2 r0 = rec2[i];
        int2 r1 = rec2[i + 1];
        int2 r2 = rec2[i + 2];
        int2 r3 = rec2[i + 3];
        float h0 = bf2f(h[(size_t)(r0.x & 0xFFFFF) * D_FEAT + lane]);
        float h1 = bf2f(h[(size_t)(r1.x & 0xFFFFF) * D_FEAT + lane]);
        float h2 = bf2f(h[(size_t)(r2.x & 0xFFFFF) * D_FEAT + lane]);
        float h3 = bf2f(h[(size_t)(r3.x & 0xFFFFF) * D_FEAT + lane]);
        a0 += __int_as_float(r0.y) * h0;
        a1 += __int_as_float(r1.y) * h1;
        a2 += __int_as_float(r2.y) * h2;
        a3 += __int_as_float(r3.y) * h3;
    }
    for (; i < end; ++i) {
        int2 r = rec2[i];
        a0 += __int_as_float(r.y) * bf2f(h[(size_t)(r.x & 0xFFFFF) * D_FEAT + lane]);
    }
    agg[(size_t)node * D_FEAT + lane] = (a0 + a1) + (a2 + a3);
}

// ---------------------------------------------------------------------------
// Fallback scatter (atomics) if workspace too small / shape unsupported
// ---------------------------------------------------------------------------
__global__ __launch_bounds__(256) void scatter_atomic_kernel(
    const int* __restrict__ eidx, const float* __restrict__ w,
    const unsigned short* __restrict__ h, float* __restrict__ agg, int n_edges)
{
    long long t = (long long)blockIdx.x * blockDim.x + threadIdx.x;
    int e = (int)(t >> 4);
    if (e >= n_edges) return;
    int c = ((int)t & 15) * 4;
    int dst = eidx[e];
    int src = eidx[n_edges + e];
    float wv = w[e];
    const unsigned short* hp = h + (size_t)src * D_FEAT + c;
    float* p = agg + (size_t)dst * D_FEAT + c;
    unsafeAtomicAdd(p + 0, wv * bf2f(hp[0]));
    unsafeAtomicAdd(p + 1, wv * bf2f(hp[1]));
    unsafeAtomicAdd(p + 2, wv * bf2f(hp[2]));
    unsafeAtomicAdd(p + 3, wv * bf2f(hp[3]));
}

// ---------------------------------------------------------------------------
// GraphNorm, parallelized: partial reduce -> finalize -> apply.
// ---------------------------------------------------------------------------
__global__ __launch_bounds__(256) void norm_part_kernel(
    const float* __restrict__ io, float* __restrict__ part, int npg)
{
    const int g = blockIdx.x / NSPLIT;
    const int s = blockIdx.x % NSPLIT;
    const int t = threadIdx.x;
    const int j = t & 63;
    const int r = t >> 6;
    const int chunk = (npg + NSPLIT - 1) / NSPLIT;
    const int n0 = s * chunk;
    const int n1 = min(npg, n0 + chunk);
    const size_t base = (size_t)g * npg * D_FEAT;

    float sum = 0.f, sq = 0.f;
    for (int n = n0 + r; n < n1; n += 4) {
        float v = io[base + (size_t)n * D_FEAT + j];
        sum += v; sq += v * v;
    }
    __shared__ float s_red[2][4][64];
    s_red[0][r][j] = sum;
    s_red[1][r][j] = sq;
    __syncthreads();
    if (r == 0) {
        float S = s_red[0][0][j] + s_red[0][1][j] + s_red[0][2][j] + s_red[0][3][j];
        float Q = s_red[1][0][j] + s_red[1][1][j] + s_red[1][2][j] + s_red[1][3][j];
        part[(size_t)blockIdx.x * 128 + j]      = S;
        part[(size_t)blockIdx.x * 128 + 64 + j] = Q;
    }
}

__global__ __launch_bounds__(64) void norm_fin_kernel(
    const float* __restrict__ part, float* __restrict__ musc,
    const float* __restrict__ gamma, int npg)
{
    const int g = blockIdx.x;
    const int j = threadIdx.x;
    float S = 0.f, Q = 0.f;
    #pragma unroll
    for (int s = 0; s < NSPLIT; ++s) {
        S += part[(size_t)(g * NSPLIT + s) * 128 + j];
        Q += part[(size_t)(g * NSPLIT + s) * 128 + 64 + j];
    }
    float cnt = (float)npg;
    float mu = S / cnt;
    float var = (Q - cnt * mu * mu) / fmaxf(cnt - 1.f, 1.f);
    var = fmaxf(var, 0.f);
    musc[g * 128 + j]      = mu;
    musc[g * 128 + 64 + j] = gamma[j] / (sqrtf(var) + EPS_N);
}

__global__ __launch_bounds__(256) void norm_apply_kernel(
    float* __restrict__ io, const float* __restrict__ musc,
    const float* __restrict__ beta, int n_nodes, int npg)
{
    const int nf4 = n_nodes * 16;   // float4 count
    for (int i4 = blockIdx.x * blockDim.x + threadIdx.x; i4 < nf4;
         i4 += gridDim.x * blockDim.x) {
        int node = i4 >> 4;
        int j0 = (i4 & 15) * 4;
        int g = node / npg;
        float4 v  = *reinterpret_cast<float4*>(io + (size_t)i4 * 4);
        float4 mu = *reinterpret_cast<const float4*>(musc + g * 128 + j0);
        float4 sc = *reinterpret_cast<const float4*>(musc + g * 128 + 64 + j0);
        float4 be = *reinterpret_cast<const float4*>(beta + j0);
        v.x = (v.x - mu.x) * sc.x + be.x;
        v.y = (v.y - mu.y) * sc.y + be.y;
        v.z = (v.z - mu.z) * sc.z + be.z;
        v.w = (v.w - mu.w) * sc.w + be.w;
        *reinterpret_cast<float4*>(io + (size_t)i4 * 4) = v;
    }
}

extern "C" void kernel_launch(void* const* d_in, const int* in_sizes, int n_in,
                              void* d_out, int out_size, void* d_ws, size_t ws_size,
                              hipStream_t stream)
{
    const float* x      = (const float*)d_in[0];
    const float* states = (const float*)d_in[1];
    const int*   eidx   = (const int*)d_in[2];
    const float* w      = (const float*)d_in[3];
    const float* Ws     = (const float*)d_in[6];
    const float* W1     = (const float*)d_in[7];
    const float* W2     = (const float*)d_in[8];
    const float* gamma  = (const float*)d_in[9];
    const float* beta   = (const float*)d_in[10];

    const int n_nodes  = in_sizes[0] / D_FEAT;
    const int n_edges  = in_sizes[3];
    const int n_graphs = in_sizes[5];
    const int npg      = n_nodes / n_graphs;

    const int nb  = (n_nodes + BUCKET_NODES - 1) / BUCKET_NODES;  // 391
    const int nch = (n_edges + CHUNK_E - 1) / CHUNK_E;            // 293
    const int nscan = nb * nch;

    // workspace layout: h(bf16) | rec | rec2 | bh | partials | row_start
    char* ws = (char*)d_ws;
    size_t hBytes    = ((size_t)n_nodes * D_FEAT * sizeof(unsigned short) + 15) & ~15ULL;
    size_t recBytes  = (size_t)n_edges * sizeof(int2);
    size_t bhBytes   = (size_t)nscan * sizeof(int);
    size_t partBytes = 256 * sizeof(int);
    size_t rsBytes   = (size_t)(n_nodes + 1) * sizeof(int);
    size_t need = hBytes + 2 * recBytes + bhBytes + partBytes + rsBytes;

    unsigned short* h = (unsigned short*)ws;
    float* agg = (float*)d_out;

    // norm scratch aliases the rec region (rec dead before norm runs)
    float* nrm_part = (float*)(ws + hBytes);
    float* nrm_musc = nrm_part + (size_t)n_graphs * NSPLIT * 128;

    mlp_kernel<<<(n_nodes + 63) / 64, 256, 0, stream>>>(x, states, Ws, W1, W2, h, n_nodes);

    const bool ok = (ws_size >= need) && (nb <= NB_MAX) && (n_nodes < (1 << 20));
    if (ok) {
        int2* rec      = (int2*)(ws + hBytes);
        int2* rec2     = (int2*)(ws + hBytes + recBytes);
        int*  bh       = (int*)(ws + hBytes + 2 * recBytes);
        int*  partials = (int*)(ws + hBytes + 2 * recBytes + bhBytes);
        int*  row_start= (int*)(ws + hBytes + 2 * recBytes + bhBytes + partBytes);

        binhist_kernel<<<nch, 256, 0, stream>>>(eidx, bh, n_edges, nb, nch);

        int nchunks = (nscan + SCAN_CHUNK - 1) / SCAN_CHUNK;
        scan1_kernel<<<nchunks, 256, 0, stream>>>(bh, bh, partials, nscan);  // in-place
        scan2_kernel<<<1, 256, 0, stream>>>(partials, nchunks);

        binscatter_kernel<<<nch, 256, 0, stream>>>(eidx, w, bh, partials, rec,
                                                   n_edges, nb, nch);

        bucket_sort_kernel<<<nb, 256, 0, stream>>>(bh, partials, rec, rec2, row_start,
                                                   n_edges, nb, nch, n_nodes);

        node_gather_kernel<<<(n_nodes + 3) / 4, 256, 0, stream>>>(row_start, rec2, h,
                                                                  agg, n_nodes);
    } else {
        hipMemsetAsync(agg, 0, (size_t)n_nodes * D_FEAT * sizeof(float), stream);
        long long sthreads = (long long)n_edges * 16;
        int sblocks = (int)((sthreads + 255) / 256);
        scatter_atomic_kernel<<<sblocks, 256, 0, stream>>>(eidx, w, h, agg, n_edges);
    }

    norm_part_kernel<<<n_graphs * NSPLIT, 256, 0, stream>>>(agg, nrm_part, npg);
    norm_fin_kernel<<<n_graphs, 64, 0, stream>>>(nrm_part, nrm_musc, gamma, npg);
    norm_apply_kernel<<<1024, 256, 0, stream>>>(agg, nrm_musc, beta, n_nodes, npg);
}

// Round 17
// 134.866 us; speedup vs baseline: 2.0484x; 1.2745x over previous
//
#include <hip/hip_runtime.h>

#define D_FEAT 64
constexpr float SLOPE = 0.01f;
constexpr float EPS_N = 1e-6f;
constexpr int SCAN_CHUNK = 2048;   // elements per scan block (256 thr x 8)
constexpr int CHUNK_E = 4096;      // edges per binning block
constexpr int BUCKET_SHIFT = 8;    // 256 nodes per bucket
constexpr int BUCKET_NODES = 256;
constexpr int NB_MAX = 512;        // max buckets supported by LDS hist
constexpr int NSPLIT = 8;          // blocks per graph for norm partial reduce
constexpr int AP = 72;             // act/wmat LDS pitch in bf16 elems (144B: 16B-aligned, 2-way banks)

__device__ __forceinline__ float lrelu(float v) { return v >= 0.f ? v : SLOPE * v; }

// bf16 round-to-nearest-even
__device__ __forceinline__ unsigned short f2bf(float f) {
    union { float f; unsigned u; } v; v.f = f;
    unsigned r = v.u + 0x7FFF + ((v.u >> 16) & 1);
    return (unsigned short)(r >> 16);
}
__device__ __forceinline__ float bf2f(unsigned short b) {
    union { unsigned u; float f; } v; v.u = (unsigned)b << 16;
    return v.f;
}

typedef short bf16x8 __attribute__((ext_vector_type(8)));
typedef float f32x4  __attribute__((ext_vector_type(4)));

// ---------------------------------------------------------------------------
// MFMA MLP: h = (lrelu(lrelu(x + states@Ws^T) @ W1^T)) @ W2^T, h stored bf16.
// Block = 64 nodes x 64 ch, 4 waves; wave w owns node rows 16w..16w+15.
// act LDS tile is WAVE-PRIVATE -> no barriers on act; wmat restage needs 6.
// mfma_f32_16x16x32_bf16: D col=lane&15, row=4*(lane>>4)+reg (m89-verified).
// A and B both loaded 8-contiguous-k from row-major: any consistent per-lane
// k-permutation cancels in the dot product, so only row/col mappings matter.
// R16 BUG (fixed): h-out copied one uint4 (8 bf16) per 16-elem segment ->
// half of h was poison. Now 2x uint4 per segment.
// ---------------------------------------------------------------------------
__global__ __launch_bounds__(256, 4) void mlp_kernel(
    const float* __restrict__ x, const float* __restrict__ states,
    const float* __restrict__ Ws, const float* __restrict__ W1,
    const float* __restrict__ W2, unsigned short* __restrict__ h, int n_nodes)
{
    __shared__ __align__(16) unsigned short act[64 * AP];    // 9216 B
    __shared__ __align__(16) unsigned short wmat[64 * AP];   // 9216 B

    const int t    = threadIdx.x;
    const int lane = t & 63;
    const int wv   = t >> 6;        // wave id 0..3
    const int fr   = lane & 15;     // fragment row/col
    const int fq   = lane >> 4;     // quarter 0..3
    const int nbase = blockIdx.x * 64;

    // weight stage: thread t converts W[row][seg*16..+15] (row = t>>2, seg = t&3)
#define STAGE_WMAT(Wp)                                                        \
    {                                                                         \
        const int row = t >> 2, seg = t & 3;                                  \
        const float* p = (Wp) + row * 64 + seg * 16;                          \
        unsigned short* d = wmat + row * AP + seg * 16;                       \
        _Pragma("unroll")                                                     \
        for (int q = 0; q < 4; ++q) {                                         \
            float4 v = reinterpret_cast<const float4*>(p)[q];                 \
            d[q * 4 + 0] = f2bf(v.x); d[q * 4 + 1] = f2bf(v.y);               \
            d[q * 4 + 2] = f2bf(v.z); d[q * 4 + 3] = f2bf(v.w);               \
        }                                                                     \
    }

    // ---- stage states -> act (bf16); rows t>>2 are wave-private ----
    {
        const int row = t >> 2, seg = t & 3;
        const int node = nbase + row;
        float4 v[4];
        if (node < n_nodes) {
            const float* p = states + (size_t)node * 64 + seg * 16;
            #pragma unroll
            for (int q = 0; q < 4; ++q) v[q] = reinterpret_cast<const float4*>(p)[q];
        } else {
            #pragma unroll
            for (int q = 0; q < 4; ++q) v[q] = make_float4(0.f, 0.f, 0.f, 0.f);
        }
        unsigned short* d = act + row * AP + seg * 16;
        #pragma unroll
        for (int q = 0; q < 4; ++q) {
            d[q * 4 + 0] = f2bf(v[q].x); d[q * 4 + 1] = f2bf(v[q].y);
            d[q * 4 + 2] = f2bf(v[q].z); d[q * 4 + 3] = f2bf(v[q].w);
        }
    }
    STAGE_WMAT(Ws);
    __syncthreads();   // wmat(Ws) ready

    f32x4 acc[4];

    // A-frag source for this wave: act[(16*wv + fr)*AP + kk*32 + fq*8]
    const unsigned short* aptr = act + (16 * wv + fr) * AP + fq * 8;

#define MFMA_STAGE()                                                          \
    _Pragma("unroll")                                                         \
    for (int kk = 0; kk < 2; ++kk) {                                          \
        bf16x8 a = *reinterpret_cast<const bf16x8*>(aptr + kk * 32);          \
        _Pragma("unroll")                                                     \
        for (int ct = 0; ct < 4; ++ct) {                                      \
            bf16x8 b = *reinterpret_cast<const bf16x8*>(                      \
                wmat + (16 * ct + fr) * AP + kk * 32 + fq * 8);               \
            acc[ct] = __builtin_amdgcn_mfma_f32_16x16x32_bf16(a, b, acc[ct], 0, 0, 0); \
        }                                                                     \
    }

    // writeback lrelu(acc) -> act rows 16wv+4fq+r (wave-private)
#define WRITEBACK_LRELU()                                                     \
    _Pragma("unroll")                                                         \
    for (int ct = 0; ct < 4; ++ct)                                            \
        _Pragma("unroll")                                                     \
        for (int r = 0; r < 4; ++r)                                           \
            act[(16 * wv + 4 * fq + r) * AP + 16 * ct + fr] = f2bf(lrelu(acc[ct][r]));

    // ---- stage 1: acc = x; acc += states @ Ws^T; act = lrelu(acc) ----
    #pragma unroll
    for (int ct = 0; ct < 4; ++ct) {
        #pragma unroll
        for (int r = 0; r < 4; ++r) {
            int node = nbase + 16 * wv + 4 * fq + r;
            acc[ct][r] = (node < n_nodes) ? x[(size_t)node * 64 + 16 * ct + fr] : 0.f;
        }
    }
    MFMA_STAGE();
    WRITEBACK_LRELU();
    __syncthreads();   // all wmat(Ws) reads done
    STAGE_WMAT(W1);
    __syncthreads();   // wmat(W1) ready

    // ---- stage 2 ----
    #pragma unroll
    for (int ct = 0; ct < 4; ++ct) acc[ct] = (f32x4){0.f, 0.f, 0.f, 0.f};
    MFMA_STAGE();
    WRITEBACK_LRELU();
    __syncthreads();   // all wmat(W1) reads done
    STAGE_WMAT(W2);
    __syncthreads();   // wmat(W2) ready

    // ---- stage 3: h = act @ W2^T (no lrelu) ----
    #pragma unroll
    for (int ct = 0; ct < 4; ++ct) acc[ct] = (f32x4){0.f, 0.f, 0.f, 0.f};
    MFMA_STAGE();
    #pragma unroll
    for (int ct = 0; ct < 4; ++ct)
        #pragma unroll
        for (int r = 0; r < 4; ++r)
            act[(16 * wv + 4 * fq + r) * AP + 16 * ct + fr] = f2bf(acc[ct][r]);
    // no barrier: h-out below reads this wave's own rows

    // ---- coalesced h out: thread t copies act[t>>2][seg*16..+15] = 32B ----
    {
        const int row = t >> 2, seg = t & 3;
        const int node = nbase + row;
        if (node < n_nodes) {
            const uint4* s = reinterpret_cast<const uint4*>(act + row * AP + seg * 16);
            uint4* d = reinterpret_cast<uint4*>(h + (size_t)node * 64 + seg * 16);
            d[0] = s[0];   // bf16 elems 0..7 of this 16-elem segment
            d[1] = s[1];   // bf16 elems 8..15 (R16 bug: this half was missing)
        }
    }
#undef STAGE_WMAT
#undef MFMA_STAGE
#undef WRITEBACK_LRELU
}

// ---------------------------------------------------------------------------
// Pass A: per-chunk bucket histogram (bucket = dst >> BUCKET_SHIFT).
// ---------------------------------------------------------------------------
__global__ __launch_bounds__(256) void binhist_kernel(
    const int* __restrict__ eidx, int* __restrict__ bh,
    int n_edges, int nb, int nch)
{
    __shared__ int hist[NB_MAX];
    const int c = blockIdx.x, t = threadIdx.x;
    for (int i = t; i < nb; i += 256) hist[i] = 0;
    __syncthreads();
    const int base = c * CHUNK_E;
    #pragma unroll 4
    for (int k = 0; k < CHUNK_E / 256; ++k) {
        int e = base + k * 256 + t;
        if (e < n_edges) atomicAdd(&hist[eidx[e] >> BUCKET_SHIFT], 1);
    }
    __syncthreads();
    for (int i = t; i < nb; i += 256) bh[i * nch + c] = hist[i];
}

// ---------------------------------------------------------------------------
// Scan: local exclusive per 2048-chunk (scan1) + partials scan (scan2).
// Consumers add partials[idx/SCAN_CHUNK] inline.
// ---------------------------------------------------------------------------
__global__ __launch_bounds__(256) void scan1_kernel(
    const int* __restrict__ in, int* __restrict__ out,
    int* __restrict__ partials, int n)
{
    __shared__ int s[256];
    const int b = blockIdx.x, t = threadIdx.x;
    const int base = b * SCAN_CHUNK + t * 8;
    int v[8]; int sum = 0;
    #pragma unroll
    for (int i = 0; i < 8; ++i) {
        v[i] = (base + i < n) ? in[base + i] : 0;
        sum += v[i];
    }
    s[t] = sum;
    __syncthreads();
    for (int off = 1; off < 256; off <<= 1) {
        int y = (t >= off) ? s[t - off] : 0;
        __syncthreads();
        s[t] += y;
        __syncthreads();
    }
    int excl = s[t] - sum;
    #pragma unroll
    for (int i = 0; i < 8; ++i) {
        if (base + i < n) out[base + i] = excl;
        excl += v[i];
    }
    if (t == 255) partials[b] = s[255];
}

__global__ __launch_bounds__(256) void scan2_kernel(int* partials, int nchunks)
{
    __shared__ int s[256];
    const int t = threadIdx.x;
    int v = (t < nchunks) ? partials[t] : 0;
    s[t] = v;
    __syncthreads();
    for (int off = 1; off < 256; off <<= 1) {
        int y = (t >= off) ? s[t - off] : 0;
        __syncthreads();
        s[t] += y;
        __syncthreads();
    }
    if (t < nchunks) partials[t] = s[t] - v;      // exclusive
}

// ---------------------------------------------------------------------------
// Pass B: binned scatter into per-(bucket,chunk) contiguous runs.
// rec.x = (dstLocal << 20) | src,  rec.y = w bits.
// ---------------------------------------------------------------------------
__global__ __launch_bounds__(256) void binscatter_kernel(
    const int* __restrict__ eidx, const float* __restrict__ w,
    const int* __restrict__ bh, const int* __restrict__ partials,
    int2* __restrict__ rec, int n_edges, int nb, int nch)
{
    __shared__ int cur[NB_MAX];
    const int c = blockIdx.x, t = threadIdx.x;
    for (int i = t; i < nb; i += 256) {
        int idx = i * nch + c;
        cur[i] = bh[idx] + partials[idx / SCAN_CHUNK];
    }
    __syncthreads();
    const int base = c * CHUNK_E;
    #pragma unroll 4
    for (int k = 0; k < CHUNK_E / 256; ++k) {
        int e = base + k * 256 + t;
        if (e < n_edges) {
            int dst = eidx[e];
            int src = eidx[n_edges + e];
            float wv = w[e];
            int b = dst >> BUCKET_SHIFT;
            int dl = dst & (BUCKET_NODES - 1);
            int pos = atomicAdd(&cur[b], 1);
            rec[pos] = make_int2((dl << 20) | src, __float_as_int(wv));
        }
    }
}

// ---------------------------------------------------------------------------
// Pass B2: per-bucket counting sort into per-NODE order + row_start build.
// ---------------------------------------------------------------------------
__global__ __launch_bounds__(256) void bucket_sort_kernel(
    const int* __restrict__ bh, const int* __restrict__ partials,
    const int2* __restrict__ rec, int2* __restrict__ rec2,
    int* __restrict__ row_start, int n_edges, int nb, int nch, int n_nodes)
{
    __shared__ int cnt[BUCKET_NODES];
    __shared__ int s[BUCKET_NODES];
    __shared__ int pos[BUCKET_NODES];

    const int b = blockIdx.x, t = threadIdx.x;
    const int iS = b * nch;
    const int S = bh[iS] + partials[iS / SCAN_CHUNK];
    int E = n_edges;
    if (b + 1 < nb) {
        int iE = (b + 1) * nch;
        E = bh[iE] + partials[iE / SCAN_CHUNK];
    }

    cnt[t] = 0;
    __syncthreads();
    for (int i = S + t; i < E; i += 256)
        atomicAdd(&cnt[rec[i].x >> 20], 1);
    __syncthreads();

    int my = cnt[t];
    s[t] = my;
    __syncthreads();
    for (int off = 1; off < 256; off <<= 1) {
        int y = (t >= off) ? s[t - off] : 0;
        __syncthreads();
        s[t] += y;
        __syncthreads();
    }
    int excl = s[t] - my;
    pos[t] = S + excl;
    const int node = (b << BUCKET_SHIFT) + t;
    if (node < n_nodes) row_start[node] = S + excl;
    if (b == nb - 1 && t == 0) row_start[n_nodes] = n_edges;
    __syncthreads();

    for (int i = S + t; i < E; i += 256) {
        int2 r = rec[i];
        int p = atomicAdd(&pos[r.x >> 20], 1);
        rec2[p] = r;
    }
}

// ---------------------------------------------------------------------------
// Pass C: atomic-free gather. One wave per destination node, lane = channel.
// h is bf16 -> per-edge row read is 128B.
// ---------------------------------------------------------------------------
__global__ __launch_bounds__(256, 8) void node_gather_kernel(
    const int* __restrict__ row_start, const int2* __restrict__ rec2,
    const unsigned short* __restrict__ h, float* __restrict__ agg, int n_nodes)
{
    const int node = blockIdx.x * 4 + (threadIdx.x >> 6);
    const int lane = threadIdx.x & 63;
    if (node >= n_nodes) return;

    const int start = row_start[node];
    const int end   = row_start[node + 1];

    float a0 = 0.f, a1 = 0.f, a2 = 0.f, a3 = 0.f;
    int i = start;
    for (; i + 4 <= end; i += 4) {
        int2 r0 = rec2[i];
        int2 r1 = rec2[i + 1];
        int2 r2 = rec2[i + 2];
        int2 r3 = rec2[i + 3];
        float h0 = bf2f(h[(size_t)(r0.x & 0xFFFFF) * D_FEAT + lane]);
        float h1 = bf2f(h[(size_t)(r1.x & 0xFFFFF) * D_FEAT + lane]);
        float h2 = bf2f(h[(size_t)(r2.x & 0xFFFFF) * D_FEAT + lane]);
        float h3 = bf2f(h[(size_t)(r3.x & 0xFFFFF) * D_FEAT + lane]);
        a0 += __int_as_float(r0.y) * h0;
        a1 += __int_as_float(r1.y) * h1;
        a2 += __int_as_float(r2.y) * h2;
        a3 += __int_as_float(r3.y) * h3;
    }
    for (; i < end; ++i) {
        int2 r = rec2[i];
        a0 += __int_as_float(r.y) * bf2f(h[(size_t)(r.x & 0xFFFFF) * D_FEAT + lane]);
    }
    agg[(size_t)node * D_FEAT + lane] = (a0 + a1) + (a2 + a3);
}

// ---------------------------------------------------------------------------
// Fallback scatter (atomics) if workspace too small / shape unsupported
// ---------------------------------------------------------------------------
__global__ __launch_bounds__(256) void scatter_atomic_kernel(
    const int* __restrict__ eidx, const float* __restrict__ w,
    const unsigned short* __restrict__ h, float* __restrict__ agg, int n_edges)
{
    long long t = (long long)blockIdx.x * blockDim.x + threadIdx.x;
    int e = (int)(t >> 4);
    if (e >= n_edges) return;
    int c = ((int)t & 15) * 4;
    int dst = eidx[e];
    int src = eidx[n_edges + e];
    float wv = w[e];
    const unsigned short* hp = h + (size_t)src * D_FEAT + c;
    float* p = agg + (size_t)dst * D_FEAT + c;
    unsafeAtomicAdd(p + 0, wv * bf2f(hp[0]));
    unsafeAtomicAdd(p + 1, wv * bf2f(hp[1]));
    unsafeAtomicAdd(p + 2, wv * bf2f(hp[2]));
    unsafeAtomicAdd(p + 3, wv * bf2f(hp[3]));
}

// ---------------------------------------------------------------------------
// GraphNorm, parallelized: partial reduce -> finalize -> apply.
// ---------------------------------------------------------------------------
__global__ __launch_bounds__(256) void norm_part_kernel(
    const float* __restrict__ io, float* __restrict__ part, int npg)
{
    const int g = blockIdx.x / NSPLIT;
    const int s = blockIdx.x % NSPLIT;
    const int t = threadIdx.x;
    const int j = t & 63;
    const int r = t >> 6;
    const int chunk = (npg + NSPLIT - 1) / NSPLIT;
    const int n0 = s * chunk;
    const int n1 = min(npg, n0 + chunk);
    const size_t base = (size_t)g * npg * D_FEAT;

    float sum = 0.f, sq = 0.f;
    for (int n = n0 + r; n < n1; n += 4) {
        float v = io[base + (size_t)n * D_FEAT + j];
        sum += v; sq += v * v;
    }
    __shared__ float s_red[2][4][64];
    s_red[0][r][j] = sum;
    s_red[1][r][j] = sq;
    __syncthreads();
    if (r == 0) {
        float S = s_red[0][0][j] + s_red[0][1][j] + s_red[0][2][j] + s_red[0][3][j];
        float Q = s_red[1][0][j] + s_red[1][1][j] + s_red[1][2][j] + s_red[1][3][j];
        part[(size_t)blockIdx.x * 128 + j]      = S;
        part[(size_t)blockIdx.x * 128 + 64 + j] = Q;
    }
}

__global__ __launch_bounds__(64) void norm_fin_kernel(
    const float* __restrict__ part, float* __restrict__ musc,
    const float* __restrict__ gamma, int npg)
{
    const int g = blockIdx.x;
    const int j = threadIdx.x;
    float S = 0.f, Q = 0.f;
    #pragma unroll
    for (int s = 0; s < NSPLIT; ++s) {
        S += part[(size_t)(g * NSPLIT + s) * 128 + j];
        Q += part[(size_t)(g * NSPLIT + s) * 128 + 64 + j];
    }
    float cnt = (float)npg;
    float mu = S / cnt;
    float var = (Q - cnt * mu * mu) / fmaxf(cnt - 1.f, 1.f);
    var = fmaxf(var, 0.f);
    musc[g * 128 + j]      = mu;
    musc[g * 128 + 64 + j] = gamma[j] / (sqrtf(var) + EPS_N);
}

__global__ __launch_bounds__(256) void norm_apply_kernel(
    float* __restrict__ io, const float* __restrict__ musc,
    const float* __restrict__ beta, int n_nodes, int npg)
{
    const int nf4 = n_nodes * 16;   // float4 count
    for (int i4 = blockIdx.x * blockDim.x + threadIdx.x; i4 < nf4;
         i4 += gridDim.x * blockDim.x) {
        int node = i4 >> 4;
        int j0 = (i4 & 15) * 4;
        int g = node / npg;
        float4 v  = *reinterpret_cast<float4*>(io + (size_t)i4 * 4);
        float4 mu = *reinterpret_cast<const float4*>(musc + g * 128 + j0);
        float4 sc = *reinterpret_cast<const float4*>(musc + g * 128 + 64 + j0);
        float4 be = *reinterpret_cast<const float4*>(beta + j0);
        v.x = (v.x - mu.x) * sc.x + be.x;
        v.y = (v.y - mu.y) * sc.y + be.y;
        v.z = (v.z - mu.z) * sc.z + be.z;
        v.w = (v.w - mu.w) * sc.w + be.w;
        *reinterpret_cast<float4*>(io + (size_t)i4 * 4) = v;
    }
}

extern "C" void kernel_launch(void* const* d_in, const int* in_sizes, int n_in,
                              void* d_out, int out_size, void* d_ws, size_t ws_size,
                              hipStream_t stream)
{
    const float* x      = (const float*)d_in[0];
    const float* states = (const float*)d_in[1];
    const int*   eidx   = (const int*)d_in[2];
    const float* w      = (const float*)d_in[3];
    const float* Ws     = (const float*)d_in[6];
    const float* W1     = (const float*)d_in[7];
    const float* W2     = (const float*)d_in[8];
    const float* gamma  = (const float*)d_in[9];
    const float* beta   = (const float*)d_in[10];

    const int n_nodes  = in_sizes[0] / D_FEAT;
    const int n_edges  = in_sizes[3];
    const int n_graphs = in_sizes[5];
    const int npg      = n_nodes / n_graphs;

    const int nb  = (n_nodes + BUCKET_NODES - 1) / BUCKET_NODES;  // 391
    const int nch = (n_edges + CHUNK_E - 1) / CHUNK_E;            // 293
    const int nscan = nb * nch;

    // workspace layout: h(bf16) | rec | rec2 | bh | partials | row_start
    char* ws = (char*)d_ws;
    size_t hBytes    = ((size_t)n_nodes * D_FEAT * sizeof(unsigned short) + 15) & ~15ULL;
    size_t recBytes  = (size_t)n_edges * sizeof(int2);
    size_t bhBytes   = (size_t)nscan * sizeof(int);
    size_t partBytes = 256 * sizeof(int);
    size_t rsBytes   = (size_t)(n_nodes + 1) * sizeof(int);
    size_t need = hBytes + 2 * recBytes + bhBytes + partBytes + rsBytes;

    unsigned short* h = (unsigned short*)ws;
    float* agg = (float*)d_out;

    // norm scratch aliases the rec region (rec dead before norm runs)
    float* nrm_part = (float*)(ws + hBytes);
    float* nrm_musc = nrm_part + (size_t)n_graphs * NSPLIT * 128;

    mlp_kernel<<<(n_nodes + 63) / 64, 256, 0, stream>>>(x, states, Ws, W1, W2, h, n_nodes);

    const bool ok = (ws_size >= need) && (nb <= NB_MAX) && (n_nodes < (1 << 20));
    if (ok) {
        int2* rec      = (int2*)(ws + hBytes);
        int2* rec2     = (int2*)(ws + hBytes + recBytes);
        int*  bh       = (int*)(ws + hBytes + 2 * recBytes);
        int*  partials = (int*)(ws + hBytes + 2 * recBytes + bhBytes);
        int*  row_start= (int*)(ws + hBytes + 2 * recBytes + bhBytes + partBytes);

        binhist_kernel<<<nch, 256, 0, stream>>>(eidx, bh, n_edges, nb, nch);

        int nchunks = (nscan + SCAN_CHUNK - 1) / SCAN_CHUNK;
        scan1_kernel<<<nchunks, 256, 0, stream>>>(bh, bh, partials, nscan);  // in-place
        scan2_kernel<<<1, 256, 0, stream>>>(partials, nchunks);

        binscatter_kernel<<<nch, 256, 0, stream>>>(eidx, w, bh, partials, rec,
                                                   n_edges, nb, nch);

        bucket_sort_kernel<<<nb, 256, 0, stream>>>(bh, partials, rec, rec2, row_start,
                                                   n_edges, nb, nch, n_nodes);

        node_gather_kernel<<<(n_nodes + 3) / 4, 256, 0, stream>>>(row_start, rec2, h,
                                                                  agg, n_nodes);
    } else {
        hipMemsetAsync(agg, 0, (size_t)n_nodes * D_FEAT * sizeof(float), stream);
        long long sthreads = (long long)n_edges * 16;
        int sblocks = (int)((sthreads + 255) / 256);
        scatter_atomic_kernel<<<sblocks, 256, 0, stream>>>(eidx, w, h, agg, n_edges);
    }

    norm_part_kernel<<<n_graphs * NSPLIT, 256, 0, stream>>>(agg, nrm_part, npg);
    norm_fin_kernel<<<n_graphs, 64, 0, stream>>>(nrm_part, nrm_musc, gamma, npg);
    norm_apply_kernel<<<1024, 256, 0, stream>>>(agg, nrm_musc, beta, n_nodes, npg);
}

// Round 18
// 129.395 us; speedup vs baseline: 2.1350x; 1.0423x over previous
//
#include <hip/hip_runtime.h>

#define D_FEAT 64
constexpr float SLOPE = 0.01f;
constexpr float EPS_N = 1e-6f;
constexpr int SCAN_CHUNK = 2048;   // elements per scan block (256 thr x 8)
constexpr int CHUNK_E = 4096;      // edges per binning block
constexpr int BUCKET_SHIFT = 8;    // 256 nodes per bucket
constexpr int BUCKET_NODES = 256;
constexpr int NB_MAX = 512;        // max buckets supported by LDS hist
constexpr int NSPLIT = 8;          // blocks per graph for norm partial reduce
constexpr int AP = 72;             // act/wmat LDS pitch in bf16 elems

__device__ __forceinline__ float lrelu(float v) { return v >= 0.f ? v : SLOPE * v; }

// bf16 round-to-nearest-even
__device__ __forceinline__ unsigned short f2bf(float f) {
    union { float f; unsigned u; } v; v.f = f;
    unsigned r = v.u + 0x7FFF + ((v.u >> 16) & 1);
    return (unsigned short)(r >> 16);
}
__device__ __forceinline__ float bf2f(unsigned short b) {
    union { unsigned u; float f; } v; v.u = (unsigned)b << 16;
    return v.f;
}

typedef short bf16x8 __attribute__((ext_vector_type(8)));
typedef float f32x4  __attribute__((ext_vector_type(4)));

// ---------------------------------------------------------------------------
// MFMA MLP (R17, verified): h = lrelu-chain MLP, h stored bf16.
// Block = 64 nodes x 64 ch, 4 waves; act LDS tile wave-private.
// ---------------------------------------------------------------------------
__global__ __launch_bounds__(256, 4) void mlp_kernel(
    const float* __restrict__ x, const float* __restrict__ states,
    const float* __restrict__ Ws, const float* __restrict__ W1,
    const float* __restrict__ W2, unsigned short* __restrict__ h, int n_nodes)
{
    __shared__ __align__(16) unsigned short act[64 * AP];    // 9216 B
    __shared__ __align__(16) unsigned short wmat[64 * AP];   // 9216 B

    const int t    = threadIdx.x;
    const int lane = t & 63;
    const int wv   = t >> 6;
    const int fr   = lane & 15;
    const int fq   = lane >> 4;
    const int nbase = blockIdx.x * 64;

#define STAGE_WMAT(Wp)                                                        \
    {                                                                         \
        const int row = t >> 2, seg = t & 3;                                  \
        const float* p = (Wp) + row * 64 + seg * 16;                          \
        unsigned short* d = wmat + row * AP + seg * 16;                       \
        _Pragma("unroll")                                                     \
        for (int q = 0; q < 4; ++q) {                                         \
            float4 v = reinterpret_cast<const float4*>(p)[q];                 \
            d[q * 4 + 0] = f2bf(v.x); d[q * 4 + 1] = f2bf(v.y);               \
            d[q * 4 + 2] = f2bf(v.z); d[q * 4 + 3] = f2bf(v.w);               \
        }                                                                     \
    }

    {
        const int row = t >> 2, seg = t & 3;
        const int node = nbase + row;
        float4 v[4];
        if (node < n_nodes) {
            const float* p = states + (size_t)node * 64 + seg * 16;
            #pragma unroll
            for (int q = 0; q < 4; ++q) v[q] = reinterpret_cast<const float4*>(p)[q];
        } else {
            #pragma unroll
            for (int q = 0; q < 4; ++q) v[q] = make_float4(0.f, 0.f, 0.f, 0.f);
        }
        unsigned short* d = act + row * AP + seg * 16;
        #pragma unroll
        for (int q = 0; q < 4; ++q) {
            d[q * 4 + 0] = f2bf(v[q].x); d[q * 4 + 1] = f2bf(v[q].y);
            d[q * 4 + 2] = f2bf(v[q].z); d[q * 4 + 3] = f2bf(v[q].w);
        }
    }
    STAGE_WMAT(Ws);
    __syncthreads();

    f32x4 acc[4];
    const unsigned short* aptr = act + (16 * wv + fr) * AP + fq * 8;

#define MFMA_STAGE()                                                          \
    _Pragma("unroll")                                                         \
    for (int kk = 0; kk < 2; ++kk) {                                          \
        bf16x8 a = *reinterpret_cast<const bf16x8*>(aptr + kk * 32);          \
        _Pragma("unroll")                                                     \
        for (int ct = 0; ct < 4; ++ct) {                                      \
            bf16x8 b = *reinterpret_cast<const bf16x8*>(                      \
                wmat + (16 * ct + fr) * AP + kk * 32 + fq * 8);               \
            acc[ct] = __builtin_amdgcn_mfma_f32_16x16x32_bf16(a, b, acc[ct], 0, 0, 0); \
        }                                                                     \
    }

#define WRITEBACK_LRELU()                                                     \
    _Pragma("unroll")                                                         \
    for (int ct = 0; ct < 4; ++ct)                                            \
        _Pragma("unroll")                                                     \
        for (int r = 0; r < 4; ++r)                                           \
            act[(16 * wv + 4 * fq + r) * AP + 16 * ct + fr] = f2bf(lrelu(acc[ct][r]));

    #pragma unroll
    for (int ct = 0; ct < 4; ++ct) {
        #pragma unroll
        for (int r = 0; r < 4; ++r) {
            int node = nbase + 16 * wv + 4 * fq + r;
            acc[ct][r] = (node < n_nodes) ? x[(size_t)node * 64 + 16 * ct + fr] : 0.f;
        }
    }
    MFMA_STAGE();
    WRITEBACK_LRELU();
    __syncthreads();
    STAGE_WMAT(W1);
    __syncthreads();

    #pragma unroll
    for (int ct = 0; ct < 4; ++ct) acc[ct] = (f32x4){0.f, 0.f, 0.f, 0.f};
    MFMA_STAGE();
    WRITEBACK_LRELU();
    __syncthreads();
    STAGE_WMAT(W2);
    __syncthreads();

    #pragma unroll
    for (int ct = 0; ct < 4; ++ct) acc[ct] = (f32x4){0.f, 0.f, 0.f, 0.f};
    MFMA_STAGE();
    #pragma unroll
    for (int ct = 0; ct < 4; ++ct)
        #pragma unroll
        for (int r = 0; r < 4; ++r)
            act[(16 * wv + 4 * fq + r) * AP + 16 * ct + fr] = f2bf(acc[ct][r]);

    {
        const int row = t >> 2, seg = t & 3;
        const int node = nbase + row;
        if (node < n_nodes) {
            const uint4* s = reinterpret_cast<const uint4*>(act + row * AP + seg * 16);
            uint4* d = reinterpret_cast<uint4*>(h + (size_t)node * 64 + seg * 16);
            d[0] = s[0];
            d[1] = s[1];
        }
    }
#undef STAGE_WMAT
#undef MFMA_STAGE
#undef WRITEBACK_LRELU
}

// ---------------------------------------------------------------------------
// Pass A: per-chunk bucket histogram (bucket = dst >> BUCKET_SHIFT).
// ---------------------------------------------------------------------------
__global__ __launch_bounds__(256) void binhist_kernel(
    const int* __restrict__ eidx, int* __restrict__ bh,
    int n_edges, int nb, int nch)
{
    __shared__ int hist[NB_MAX];
    const int c = blockIdx.x, t = threadIdx.x;
    for (int i = t; i < nb; i += 256) hist[i] = 0;
    __syncthreads();
    const int base = c * CHUNK_E;
    #pragma unroll 4
    for (int k = 0; k < CHUNK_E / 256; ++k) {
        int e = base + k * 256 + t;
        if (e < n_edges) atomicAdd(&hist[eidx[e] >> BUCKET_SHIFT], 1);
    }
    __syncthreads();
    for (int i = t; i < nb; i += 256) bh[i * nch + c] = hist[i];
}

// ---------------------------------------------------------------------------
// Scan: local exclusive per 2048-chunk (scan1) + partials scan (scan2).
// ---------------------------------------------------------------------------
__global__ __launch_bounds__(256) void scan1_kernel(
    const int* __restrict__ in, int* __restrict__ out,
    int* __restrict__ partials, int n)
{
    __shared__ int s[256];
    const int b = blockIdx.x, t = threadIdx.x;
    const int base = b * SCAN_CHUNK + t * 8;
    int v[8]; int sum = 0;
    #pragma unroll
    for (int i = 0; i < 8; ++i) {
        v[i] = (base + i < n) ? in[base + i] : 0;
        sum += v[i];
    }
    s[t] = sum;
    __syncthreads();
    for (int off = 1; off < 256; off <<= 1) {
        int y = (t >= off) ? s[t - off] : 0;
        __syncthreads();
        s[t] += y;
        __syncthreads();
    }
    int excl = s[t] - sum;
    #pragma unroll
    for (int i = 0; i < 8; ++i) {
        if (base + i < n) out[base + i] = excl;
        excl += v[i];
    }
    if (t == 255) partials[b] = s[255];
}

__global__ __launch_bounds__(256) void scan2_kernel(int* partials, int nchunks)
{
    __shared__ int s[256];
    const int t = threadIdx.x;
    int v = (t < nchunks) ? partials[t] : 0;
    s[t] = v;
    __syncthreads();
    for (int off = 1; off < 256; off <<= 1) {
        int y = (t >= off) ? s[t - off] : 0;
        __syncthreads();
        s[t] += y;
        __syncthreads();
    }
    if (t < nchunks) partials[t] = s[t] - v;      // exclusive
}

// ---------------------------------------------------------------------------
// Pass B: binned scatter into per-(bucket,chunk) contiguous runs.
// ---------------------------------------------------------------------------
__global__ __launch_bounds__(256) void binscatter_kernel(
    const int* __restrict__ eidx, const float* __restrict__ w,
    const int* __restrict__ bh, const int* __restrict__ partials,
    int2* __restrict__ rec, int n_edges, int nb, int nch)
{
    __shared__ int cur[NB_MAX];
    const int c = blockIdx.x, t = threadIdx.x;
    for (int i = t; i < nb; i += 256) {
        int idx = i * nch + c;
        cur[i] = bh[idx] + partials[idx / SCAN_CHUNK];
    }
    __syncthreads();
    const int base = c * CHUNK_E;
    #pragma unroll 4
    for (int k = 0; k < CHUNK_E / 256; ++k) {
        int e = base + k * 256 + t;
        if (e < n_edges) {
            int dst = eidx[e];
            int src = eidx[n_edges + e];
            float wv = w[e];
            int b = dst >> BUCKET_SHIFT;
            int dl = dst & (BUCKET_NODES - 1);
            int pos = atomicAdd(&cur[b], 1);
            rec[pos] = make_int2((dl << 20) | src, __float_as_int(wv));
        }
    }
}

// ---------------------------------------------------------------------------
// Pass B2: per-bucket counting sort into per-NODE order + row_start build.
// ---------------------------------------------------------------------------
__global__ __launch_bounds__(256) void bucket_sort_kernel(
    const int* __restrict__ bh, const int* __restrict__ partials,
    const int2* __restrict__ rec, int2* __restrict__ rec2,
    int* __restrict__ row_start, int n_edges, int nb, int nch, int n_nodes)
{
    __shared__ int cnt[BUCKET_NODES];
    __shared__ int s[BUCKET_NODES];
    __shared__ int pos[BUCKET_NODES];

    const int b = blockIdx.x, t = threadIdx.x;
    const int iS = b * nch;
    const int S = bh[iS] + partials[iS / SCAN_CHUNK];
    int E = n_edges;
    if (b + 1 < nb) {
        int iE = (b + 1) * nch;
        E = bh[iE] + partials[iE / SCAN_CHUNK];
    }

    cnt[t] = 0;
    __syncthreads();
    for (int i = S + t; i < E; i += 256)
        atomicAdd(&cnt[rec[i].x >> 20], 1);
    __syncthreads();

    int my = cnt[t];
    s[t] = my;
    __syncthreads();
    for (int off = 1; off < 256; off <<= 1) {
        int y = (t >= off) ? s[t - off] : 0;
        __syncthreads();
        s[t] += y;
        __syncthreads();
    }
    int excl = s[t] - my;
    pos[t] = S + excl;
    const int node = (b << BUCKET_SHIFT) + t;
    if (node < n_nodes) row_start[node] = S + excl;
    if (b == nb - 1 && t == 0) row_start[n_nodes] = n_edges;
    __syncthreads();

    for (int i = S + t; i < E; i += 256) {
        int2 r = rec[i];
        int p = atomicAdd(&pos[r.x >> 20], 1);
        rec2[p] = r;
    }
}

// ---------------------------------------------------------------------------
// Pass C: atomic-free gather, two-phase ILP-8.
// R17 was latency-bound (VALUBusy 29%, 3x stall vs perfect overlap): the
// rec2->h dependent chain was paid every 4 edges. Now 8 independent rec2
// loads, THEN 8 independent h loads -> chain paid ~once per avg-degree node.
// ---------------------------------------------------------------------------
__global__ __launch_bounds__(256, 8) void node_gather_kernel(
    const int* __restrict__ row_start, const int2* __restrict__ rec2,
    const unsigned short* __restrict__ h, float* __restrict__ agg, int n_nodes)
{
    const int node = blockIdx.x * 4 + (threadIdx.x >> 6);
    const int lane = threadIdx.x & 63;
    if (node >= n_nodes) return;

    const int start = row_start[node];
    const int end   = row_start[node + 1];

    float a0 = 0.f, a1 = 0.f, a2 = 0.f, a3 = 0.f;
    int i = start;

    for (; i + 8 <= end; i += 8) {
        int2 r[8];
        #pragma unroll
        for (int k = 0; k < 8; ++k) r[k] = rec2[i + k];      // 8 independent
        float hv[8];
        #pragma unroll
        for (int k = 0; k < 8; ++k)                          // 8 independent
            hv[k] = bf2f(h[(size_t)(r[k].x & 0xFFFFF) * D_FEAT + lane]);
        a0 += __int_as_float(r[0].y) * hv[0];
        a1 += __int_as_float(r[1].y) * hv[1];
        a2 += __int_as_float(r[2].y) * hv[2];
        a3 += __int_as_float(r[3].y) * hv[3];
        a0 += __int_as_float(r[4].y) * hv[4];
        a1 += __int_as_float(r[5].y) * hv[5];
        a2 += __int_as_float(r[6].y) * hv[6];
        a3 += __int_as_float(r[7].y) * hv[7];
    }
    if (i + 4 <= end) {
        int2 r[4];
        #pragma unroll
        for (int k = 0; k < 4; ++k) r[k] = rec2[i + k];
        float hv[4];
        #pragma unroll
        for (int k = 0; k < 4; ++k)
            hv[k] = bf2f(h[(size_t)(r[k].x & 0xFFFFF) * D_FEAT + lane]);
        a0 += __int_as_float(r[0].y) * hv[0];
        a1 += __int_as_float(r[1].y) * hv[1];
        a2 += __int_as_float(r[2].y) * hv[2];
        a3 += __int_as_float(r[3].y) * hv[3];
        i += 4;
    }
    for (; i < end; ++i) {
        int2 r = rec2[i];
        a0 += __int_as_float(r.y) * bf2f(h[(size_t)(r.x & 0xFFFFF) * D_FEAT + lane]);
    }
    agg[(size_t)node * D_FEAT + lane] = (a0 + a1) + (a2 + a3);
}

// ---------------------------------------------------------------------------
// Fallback scatter (atomics) if workspace too small / shape unsupported
// ---------------------------------------------------------------------------
__global__ __launch_bounds__(256) void scatter_atomic_kernel(
    const int* __restrict__ eidx, const float* __restrict__ w,
    const unsigned short* __restrict__ h, float* __restrict__ agg, int n_edges)
{
    long long t = (long long)blockIdx.x * blockDim.x + threadIdx.x;
    int e = (int)(t >> 4);
    if (e >= n_edges) return;
    int c = ((int)t & 15) * 4;
    int dst = eidx[e];
    int src = eidx[n_edges + e];
    float wv = w[e];
    const unsigned short* hp = h + (size_t)src * D_FEAT + c;
    float* p = agg + (size_t)dst * D_FEAT + c;
    unsafeAtomicAdd(p + 0, wv * bf2f(hp[0]));
    unsafeAtomicAdd(p + 1, wv * bf2f(hp[1]));
    unsafeAtomicAdd(p + 2, wv * bf2f(hp[2]));
    unsafeAtomicAdd(p + 3, wv * bf2f(hp[3]));
}

// ---------------------------------------------------------------------------
// GraphNorm, parallelized: partial reduce -> finalize -> apply.
// ---------------------------------------------------------------------------
__global__ __launch_bounds__(256) void norm_part_kernel(
    const float* __restrict__ io, float* __restrict__ part, int npg)
{
    const int g = blockIdx.x / NSPLIT;
    const int s = blockIdx.x % NSPLIT;
    const int t = threadIdx.x;
    const int j = t & 63;
    const int r = t >> 6;
    const int chunk = (npg + NSPLIT - 1) / NSPLIT;
    const int n0 = s * chunk;
    const int n1 = min(npg, n0 + chunk);
    const size_t base = (size_t)g * npg * D_FEAT;

    float sum = 0.f, sq = 0.f;
    for (int n = n0 + r; n < n1; n += 4) {
        float v = io[base + (size_t)n * D_FEAT + j];
        sum += v; sq += v * v;
    }
    __shared__ float s_red[2][4][64];
    s_red[0][r][j] = sum;
    s_red[1][r][j] = sq;
    __syncthreads();
    if (r == 0) {
        float S = s_red[0][0][j] + s_red[0][1][j] + s_red[0][2][j] + s_red[0][3][j];
        float Q = s_red[1][0][j] + s_red[1][1][j] + s_red[1][2][j] + s_red[1][3][j];
        part[(size_t)blockIdx.x * 128 + j]      = S;
        part[(size_t)blockIdx.x * 128 + 64 + j] = Q;
    }
}

__global__ __launch_bounds__(64) void norm_fin_kernel(
    const float* __restrict__ part, float* __restrict__ musc,
    const float* __restrict__ gamma, int npg)
{
    const int g = blockIdx.x;
    const int j = threadIdx.x;
    float S = 0.f, Q = 0.f;
    #pragma unroll
    for (int s = 0; s < NSPLIT; ++s) {
        S += part[(size_t)(g * NSPLIT + s) * 128 + j];
        Q += part[(size_t)(g * NSPLIT + s) * 128 + 64 + j];
    }
    float cnt = (float)npg;
    float mu = S / cnt;
    float var = (Q - cnt * mu * mu) / fmaxf(cnt - 1.f, 1.f);
    var = fmaxf(var, 0.f);
    musc[g * 128 + j]      = mu;
    musc[g * 128 + 64 + j] = gamma[j] / (sqrtf(var) + EPS_N);
}

__global__ __launch_bounds__(256) void norm_apply_kernel(
    float* __restrict__ io, const float* __restrict__ musc,
    const float* __restrict__ beta, int n_nodes, int npg)
{
    const int nf4 = n_nodes * 16;   // float4 count
    for (int i4 = blockIdx.x * blockDim.x + threadIdx.x; i4 < nf4;
         i4 += gridDim.x * blockDim.x) {
        int node = i4 >> 4;
        int j0 = (i4 & 15) * 4;
        int g = node / npg;
        float4 v  = *reinterpret_cast<float4*>(io + (size_t)i4 * 4);
        float4 mu = *reinterpret_cast<const float4*>(musc + g * 128 + j0);
        float4 sc = *reinterpret_cast<const float4*>(musc + g * 128 + 64 + j0);
        float4 be = *reinterpret_cast<const float4*>(beta + j0);
        v.x = (v.x - mu.x) * sc.x + be.x;
        v.y = (v.y - mu.y) * sc.y + be.y;
        v.z = (v.z - mu.z) * sc.z + be.z;
        v.w = (v.w - mu.w) * sc.w + be.w;
        *reinterpret_cast<float4*>(io + (size_t)i4 * 4) = v;
    }
}

extern "C" void kernel_launch(void* const* d_in, const int* in_sizes, int n_in,
                              void* d_out, int out_size, void* d_ws, size_t ws_size,
                              hipStream_t stream)
{
    const float* x      = (const float*)d_in[0];
    const float* states = (const float*)d_in[1];
    const int*   eidx   = (const int*)d_in[2];
    const float* w      = (const float*)d_in[3];
    const float* Ws     = (const float*)d_in[6];
    const float* W1     = (const float*)d_in[7];
    const float* W2     = (const float*)d_in[8];
    const float* gamma  = (const float*)d_in[9];
    const float* beta   = (const float*)d_in[10];

    const int n_nodes  = in_sizes[0] / D_FEAT;
    const int n_edges  = in_sizes[3];
    const int n_graphs = in_sizes[5];
    const int npg      = n_nodes / n_graphs;

    const int nb  = (n_nodes + BUCKET_NODES - 1) / BUCKET_NODES;  // 391
    const int nch = (n_edges + CHUNK_E - 1) / CHUNK_E;            // 293
    const int nscan = nb * nch;

    // workspace layout: h(bf16) | rec | rec2 | bh | partials | row_start
    char* ws = (char*)d_ws;
    size_t hBytes    = ((size_t)n_nodes * D_FEAT * sizeof(unsigned short) + 15) & ~15ULL;
    size_t recBytes  = (size_t)n_edges * sizeof(int2);
    size_t bhBytes   = (size_t)nscan * sizeof(int);
    size_t partBytes = 256 * sizeof(int);
    size_t rsBytes   = (size_t)(n_nodes + 1) * sizeof(int);
    size_t need = hBytes + 2 * recBytes + bhBytes + partBytes + rsBytes;

    unsigned short* h = (unsigned short*)ws;
    float* agg = (float*)d_out;

    // norm scratch aliases the rec region (rec dead before norm runs)
    float* nrm_part = (float*)(ws + hBytes);
    float* nrm_musc = nrm_part + (size_t)n_graphs * NSPLIT * 128;

    mlp_kernel<<<(n_nodes + 63) / 64, 256, 0, stream>>>(x, states, Ws, W1, W2, h, n_nodes);

    const bool ok = (ws_size >= need) && (nb <= NB_MAX) && (n_nodes < (1 << 20));
    if (ok) {
        int2* rec      = (int2*)(ws + hBytes);
        int2* rec2     = (int2*)(ws + hBytes + recBytes);
        int*  bh       = (int*)(ws + hBytes + 2 * recBytes);
        int*  partials = (int*)(ws + hBytes + 2 * recBytes + bhBytes);
        int*  row_start= (int*)(ws + hBytes + 2 * recBytes + bhBytes + partBytes);

        binhist_kernel<<<nch, 256, 0, stream>>>(eidx, bh, n_edges, nb, nch);

        int nchunks = (nscan + SCAN_CHUNK - 1) / SCAN_CHUNK;
        scan1_kernel<<<nchunks, 256, 0, stream>>>(bh, bh, partials, nscan);  // in-place
        scan2_kernel<<<1, 256, 0, stream>>>(partials, nchunks);

        binscatter_kernel<<<nch, 256, 0, stream>>>(eidx, w, bh, partials, rec,
                                                   n_edges, nb, nch);

        bucket_sort_kernel<<<nb, 256, 0, stream>>>(bh, partials, rec, rec2, row_start,
                                                   n_edges, nb, nch, n_nodes);

        node_gather_kernel<<<(n_nodes + 3) / 4, 256, 0, stream>>>(row_start, rec2, h,
                                                                  agg, n_nodes);
    } else {
        hipMemsetAsync(agg, 0, (size_t)n_nodes * D_FEAT * sizeof(float), stream);
        long long sthreads = (long long)n_edges * 16;
        int sblocks = (int)((sthreads + 255) / 256);
        scatter_atomic_kernel<<<sblocks, 256, 0, stream>>>(eidx, w, h, agg, n_edges);
    }

    norm_part_kernel<<<n_graphs * NSPLIT, 256, 0, stream>>>(agg, nrm_part, npg);
    norm_fin_kernel<<<n_graphs, 64, 0, stream>>>(nrm_part, nrm_musc, gamma, npg);
    norm_apply_kernel<<<1024, 256, 0, stream>>>(agg, nrm_musc, beta, n_nodes, npg);
}

// Round 19
// 111.309 us; speedup vs baseline: 2.4819x; 1.1625x over previous
//
#include <hip/hip_runtime.h>

#define D_FEAT 64
constexpr float SLOPE = 0.01f;
constexpr float EPS_N = 1e-6f;
constexpr int SCAN_CHUNK = 2048;   // elements per scan block (256 thr x 8)
constexpr int CHUNK_E = 4096;      // edges per binning block
constexpr int BUCKET_SHIFT = 8;    // 256 nodes per bucket
constexpr int BUCKET_NODES = 256;
constexpr int NB_MAX = 512;        // max buckets supported by LDS hist
constexpr int NSPLIT = 8;          // blocks per graph for norm partial reduce
constexpr int AP = 72;             // act/wmat LDS pitch in bf16 elems

__device__ __forceinline__ float lrelu(float v) { return v >= 0.f ? v : SLOPE * v; }

// bf16 round-to-nearest-even
__device__ __forceinline__ unsigned short f2bf(float f) {
    union { float f; unsigned u; } v; v.f = f;
    unsigned r = v.u + 0x7FFF + ((v.u >> 16) & 1);
    return (unsigned short)(r >> 16);
}
__device__ __forceinline__ float bf2f(unsigned short b) {
    union { unsigned u; float f; } v; v.u = (unsigned)b << 16;
    return v.f;
}

typedef short bf16x8 __attribute__((ext_vector_type(8)));
typedef float f32x4  __attribute__((ext_vector_type(4)));

// ---------------------------------------------------------------------------
// MFMA MLP (R17, verified): h = lrelu-chain MLP, h stored bf16.
// Block = 64 nodes x 64 ch, 4 waves; act LDS tile wave-private.
// ---------------------------------------------------------------------------
__global__ __launch_bounds__(256, 4) void mlp_kernel(
    const float* __restrict__ x, const float* __restrict__ states,
    const float* __restrict__ Ws, const float* __restrict__ W1,
    const float* __restrict__ W2, unsigned short* __restrict__ h, int n_nodes)
{
    __shared__ __align__(16) unsigned short act[64 * AP];    // 9216 B
    __shared__ __align__(16) unsigned short wmat[64 * AP];   // 9216 B

    const int t    = threadIdx.x;
    const int lane = t & 63;
    const int wv   = t >> 6;
    const int fr   = lane & 15;
    const int fq   = lane >> 4;
    const int nbase = blockIdx.x * 64;

#define STAGE_WMAT(Wp)                                                        \
    {                                                                         \
        const int row = t >> 2, seg = t & 3;                                  \
        const float* p = (Wp) + row * 64 + seg * 16;                          \
        unsigned short* d = wmat + row * AP + seg * 16;                       \
        _Pragma("unroll")                                                     \
        for (int q = 0; q < 4; ++q) {                                         \
            float4 v = reinterpret_cast<const float4*>(p)[q];                 \
            d[q * 4 + 0] = f2bf(v.x); d[q * 4 + 1] = f2bf(v.y);               \
            d[q * 4 + 2] = f2bf(v.z); d[q * 4 + 3] = f2bf(v.w);               \
        }                                                                     \
    }

    {
        const int row = t >> 2, seg = t & 3;
        const int node = nbase + row;
        float4 v[4];
        if (node < n_nodes) {
            const float* p = states + (size_t)node * 64 + seg * 16;
            #pragma unroll
            for (int q = 0; q < 4; ++q) v[q] = reinterpret_cast<const float4*>(p)[q];
        } else {
            #pragma unroll
            for (int q = 0; q < 4; ++q) v[q] = make_float4(0.f, 0.f, 0.f, 0.f);
        }
        unsigned short* d = act + row * AP + seg * 16;
        #pragma unroll
        for (int q = 0; q < 4; ++q) {
            d[q * 4 + 0] = f2bf(v[q].x); d[q * 4 + 1] = f2bf(v[q].y);
            d[q * 4 + 2] = f2bf(v[q].z); d[q * 4 + 3] = f2bf(v[q].w);
        }
    }
    STAGE_WMAT(Ws);
    __syncthreads();

    f32x4 acc[4];
    const unsigned short* aptr = act + (16 * wv + fr) * AP + fq * 8;

#define MFMA_STAGE()                                                          \
    _Pragma("unroll")                                                         \
    for (int kk = 0; kk < 2; ++kk) {                                          \
        bf16x8 a = *reinterpret_cast<const bf16x8*>(aptr + kk * 32);          \
        _Pragma("unroll")                                                     \
        for (int ct = 0; ct < 4; ++ct) {                                      \
            bf16x8 b = *reinterpret_cast<const bf16x8*>(                      \
                wmat + (16 * ct + fr) * AP + kk * 32 + fq * 8);               \
            acc[ct] = __builtin_amdgcn_mfma_f32_16x16x32_bf16(a, b, acc[ct], 0, 0, 0); \
        }                                                                     \
    }

#define WRITEBACK_LRELU()                                                     \
    _Pragma("unroll")                                                         \
    for (int ct = 0; ct < 4; ++ct)                                            \
        _Pragma("unroll")                                                     \
        for (int r = 0; r < 4; ++r)                                           \
            act[(16 * wv + 4 * fq + r) * AP + 16 * ct + fr] = f2bf(lrelu(acc[ct][r]));

    #pragma unroll
    for (int ct = 0; ct < 4; ++ct) {
        #pragma unroll
        for (int r = 0; r < 4; ++r) {
            int node = nbase + 16 * wv + 4 * fq + r;
            acc[ct][r] = (node < n_nodes) ? x[(size_t)node * 64 + 16 * ct + fr] : 0.f;
        }
    }
    MFMA_STAGE();
    WRITEBACK_LRELU();
    __syncthreads();
    STAGE_WMAT(W1);
    __syncthreads();

    #pragma unroll
    for (int ct = 0; ct < 4; ++ct) acc[ct] = (f32x4){0.f, 0.f, 0.f, 0.f};
    MFMA_STAGE();
    WRITEBACK_LRELU();
    __syncthreads();
    STAGE_WMAT(W2);
    __syncthreads();

    #pragma unroll
    for (int ct = 0; ct < 4; ++ct) acc[ct] = (f32x4){0.f, 0.f, 0.f, 0.f};
    MFMA_STAGE();
    #pragma unroll
    for (int ct = 0; ct < 4; ++ct)
        #pragma unroll
        for (int r = 0; r < 4; ++r)
            act[(16 * wv + 4 * fq + r) * AP + 16 * ct + fr] = f2bf(acc[ct][r]);

    {
        const int row = t >> 2, seg = t & 3;
        const int node = nbase + row;
        if (node < n_nodes) {
            const uint4* s = reinterpret_cast<const uint4*>(act + row * AP + seg * 16);
            uint4* d = reinterpret_cast<uint4*>(h + (size_t)node * 64 + seg * 16);
            d[0] = s[0];
            d[1] = s[1];
        }
    }
#undef STAGE_WMAT
#undef MFMA_STAGE
#undef WRITEBACK_LRELU
}

// ---------------------------------------------------------------------------
// Pass A: per-chunk bucket histogram (bucket = dst >> BUCKET_SHIFT).
// ---------------------------------------------------------------------------
__global__ __launch_bounds__(256) void binhist_kernel(
    const int* __restrict__ eidx, int* __restrict__ bh,
    int n_edges, int nb, int nch)
{
    __shared__ int hist[NB_MAX];
    const int c = blockIdx.x, t = threadIdx.x;
    for (int i = t; i < nb; i += 256) hist[i] = 0;
    __syncthreads();
    const int base = c * CHUNK_E;
    #pragma unroll 4
    for (int k = 0; k < CHUNK_E / 256; ++k) {
        int e = base + k * 256 + t;
        if (e < n_edges) atomicAdd(&hist[eidx[e] >> BUCKET_SHIFT], 1);
    }
    __syncthreads();
    for (int i = t; i < nb; i += 256) bh[i * nch + c] = hist[i];
}

// ---------------------------------------------------------------------------
// Scan: local exclusive per 2048-chunk (scan1) + partials scan (scan2).
// ---------------------------------------------------------------------------
__global__ __launch_bounds__(256) void scan1_kernel(
    const int* __restrict__ in, int* __restrict__ out,
    int* __restrict__ partials, int n)
{
    __shared__ int s[256];
    const int b = blockIdx.x, t = threadIdx.x;
    const int base = b * SCAN_CHUNK + t * 8;
    int v[8]; int sum = 0;
    #pragma unroll
    for (int i = 0; i < 8; ++i) {
        v[i] = (base + i < n) ? in[base + i] : 0;
        sum += v[i];
    }
    s[t] = sum;
    __syncthreads();
    for (int off = 1; off < 256; off <<= 1) {
        int y = (t >= off) ? s[t - off] : 0;
        __syncthreads();
        s[t] += y;
        __syncthreads();
    }
    int excl = s[t] - sum;
    #pragma unroll
    for (int i = 0; i < 8; ++i) {
        if (base + i < n) out[base + i] = excl;
        excl += v[i];
    }
    if (t == 255) partials[b] = s[255];
}

__global__ __launch_bounds__(256) void scan2_kernel(int* partials, int nchunks)
{
    __shared__ int s[256];
    const int t = threadIdx.x;
    int v = (t < nchunks) ? partials[t] : 0;
    s[t] = v;
    __syncthreads();
    for (int off = 1; off < 256; off <<= 1) {
        int y = (t >= off) ? s[t - off] : 0;
        __syncthreads();
        s[t] += y;
        __syncthreads();
    }
    if (t < nchunks) partials[t] = s[t] - v;      // exclusive
}

// ---------------------------------------------------------------------------
// Pass B: binned scatter into per-(bucket,chunk) contiguous runs.
// ---------------------------------------------------------------------------
__global__ __launch_bounds__(256) void binscatter_kernel(
    const int* __restrict__ eidx, const float* __restrict__ w,
    const int* __restrict__ bh, const int* __restrict__ partials,
    int2* __restrict__ rec, int n_edges, int nb, int nch)
{
    __shared__ int cur[NB_MAX];
    const int c = blockIdx.x, t = threadIdx.x;
    for (int i = t; i < nb; i += 256) {
        int idx = i * nch + c;
        cur[i] = bh[idx] + partials[idx / SCAN_CHUNK];
    }
    __syncthreads();
    const int base = c * CHUNK_E;
    #pragma unroll 4
    for (int k = 0; k < CHUNK_E / 256; ++k) {
        int e = base + k * 256 + t;
        if (e < n_edges) {
            int dst = eidx[e];
            int src = eidx[n_edges + e];
            float wv = w[e];
            int b = dst >> BUCKET_SHIFT;
            int dl = dst & (BUCKET_NODES - 1);
            int pos = atomicAdd(&cur[b], 1);
            rec[pos] = make_int2((dl << 20) | src, __float_as_int(wv));
        }
    }
}

// ---------------------------------------------------------------------------
// Pass B2: per-bucket counting sort into per-NODE order + row_start build.
// ---------------------------------------------------------------------------
__global__ __launch_bounds__(256) void bucket_sort_kernel(
    const int* __restrict__ bh, const int* __restrict__ partials,
    const int2* __restrict__ rec, int2* __restrict__ rec2,
    int* __restrict__ row_start, int n_edges, int nb, int nch, int n_nodes)
{
    __shared__ int cnt[BUCKET_NODES];
    __shared__ int s[BUCKET_NODES];
    __shared__ int pos[BUCKET_NODES];

    const int b = blockIdx.x, t = threadIdx.x;
    const int iS = b * nch;
    const int S = bh[iS] + partials[iS / SCAN_CHUNK];
    int E = n_edges;
    if (b + 1 < nb) {
        int iE = (b + 1) * nch;
        E = bh[iE] + partials[iE / SCAN_CHUNK];
    }

    cnt[t] = 0;
    __syncthreads();
    for (int i = S + t; i < E; i += 256)
        atomicAdd(&cnt[rec[i].x >> 20], 1);
    __syncthreads();

    int my = cnt[t];
    s[t] = my;
    __syncthreads();
    for (int off = 1; off < 256; off <<= 1) {
        int y = (t >= off) ? s[t - off] : 0;
        __syncthreads();
        s[t] += y;
        __syncthreads();
    }
    int excl = s[t] - my;
    pos[t] = S + excl;
    const int node = (b << BUCKET_SHIFT) + t;
    if (node < n_nodes) row_start[node] = S + excl;
    if (b == nb - 1 && t == 0) row_start[n_nodes] = n_edges;
    __syncthreads();

    for (int i = S + t; i < E; i += 256) {
        int2 r = rec[i];
        int p = atomicAdd(&pos[r.x >> 20], 1);
        rec2[p] = r;
    }
}

// ---------------------------------------------------------------------------
// Pass C: atomic-free gather, 4 NODES PER WAVE (16-lane groups).
// R18 was still wave-serial-latency-bound: 100K waves x ~2 rounds of the
// rec2->h chain. Now each 16-lane group owns a node (lane = 4 channels via
// ushort4), so a wave runs 4 independent edge streams: wave count 4x lower,
// 4x memory-level parallelism per wave. ILP-8 per group retained.
// ---------------------------------------------------------------------------
__global__ __launch_bounds__(256, 8) void node_gather_kernel(
    const int* __restrict__ row_start, const int2* __restrict__ rec2,
    const unsigned short* __restrict__ h, float* __restrict__ agg, int n_nodes)
{
    const int wv   = threadIdx.x >> 6;
    const int lane = threadIdx.x & 63;
    const int sub  = lane >> 4;          // node slot within wave (0..3)
    const int ll   = lane & 15;          // channel group: ch 4*ll .. 4*ll+3
    const int node = blockIdx.x * 16 + wv * 4 + sub;
    if (node >= n_nodes) return;

    const int start = row_start[node];
    const int end   = row_start[node + 1];

    float a0 = 0.f, a1 = 0.f, a2 = 0.f, a3 = 0.f;
    int i = start;

    for (; i + 8 <= end; i += 8) {
        int2 r[8];
        #pragma unroll
        for (int k = 0; k < 8; ++k) r[k] = rec2[i + k];      // 8 independent
        ushort4 hv[8];
        #pragma unroll
        for (int k = 0; k < 8; ++k)                          // 8 independent 8B loads
            hv[k] = *reinterpret_cast<const ushort4*>(
                h + (size_t)(r[k].x & 0xFFFFF) * D_FEAT + ll * 4);
        #pragma unroll
        for (int k = 0; k < 8; ++k) {
            float wt = __int_as_float(r[k].y);
            a0 += wt * bf2f(hv[k].x);
            a1 += wt * bf2f(hv[k].y);
            a2 += wt * bf2f(hv[k].z);
            a3 += wt * bf2f(hv[k].w);
        }
    }
    if (i + 4 <= end) {
        int2 r[4];
        #pragma unroll
        for (int k = 0; k < 4; ++k) r[k] = rec2[i + k];
        ushort4 hv[4];
        #pragma unroll
        for (int k = 0; k < 4; ++k)
            hv[k] = *reinterpret_cast<const ushort4*>(
                h + (size_t)(r[k].x & 0xFFFFF) * D_FEAT + ll * 4);
        #pragma unroll
        for (int k = 0; k < 4; ++k) {
            float wt = __int_as_float(r[k].y);
            a0 += wt * bf2f(hv[k].x);
            a1 += wt * bf2f(hv[k].y);
            a2 += wt * bf2f(hv[k].z);
            a3 += wt * bf2f(hv[k].w);
        }
        i += 4;
    }
    for (; i < end; ++i) {
        int2 r = rec2[i];
        ushort4 hv = *reinterpret_cast<const ushort4*>(
            h + (size_t)(r.x & 0xFFFFF) * D_FEAT + ll * 4);
        float wt = __int_as_float(r.y);
        a0 += wt * bf2f(hv.x);
        a1 += wt * bf2f(hv.y);
        a2 += wt * bf2f(hv.z);
        a3 += wt * bf2f(hv.w);
    }
    float4 o = make_float4(a0, a1, a2, a3);
    *reinterpret_cast<float4*>(agg + (size_t)node * D_FEAT + ll * 4) = o;
}

// ---------------------------------------------------------------------------
// Fallback scatter (atomics) if workspace too small / shape unsupported
// ---------------------------------------------------------------------------
__global__ __launch_bounds__(256) void scatter_atomic_kernel(
    const int* __restrict__ eidx, const float* __restrict__ w,
    const unsigned short* __restrict__ h, float* __restrict__ agg, int n_edges)
{
    long long t = (long long)blockIdx.x * blockDim.x + threadIdx.x;
    int e = (int)(t >> 4);
    if (e >= n_edges) return;
    int c = ((int)t & 15) * 4;
    int dst = eidx[e];
    int src = eidx[n_edges + e];
    float wv = w[e];
    const unsigned short* hp = h + (size_t)src * D_FEAT + c;
    float* p = agg + (size_t)dst * D_FEAT + c;
    unsafeAtomicAdd(p + 0, wv * bf2f(hp[0]));
    unsafeAtomicAdd(p + 1, wv * bf2f(hp[1]));
    unsafeAtomicAdd(p + 2, wv * bf2f(hp[2]));
    unsafeAtomicAdd(p + 3, wv * bf2f(hp[3]));
}

// ---------------------------------------------------------------------------
// GraphNorm, parallelized: partial reduce -> finalize -> apply.
// ---------------------------------------------------------------------------
__global__ __launch_bounds__(256) void norm_part_kernel(
    const float* __restrict__ io, float* __restrict__ part, int npg)
{
    const int g = blockIdx.x / NSPLIT;
    const int s = blockIdx.x % NSPLIT;
    const int t = threadIdx.x;
    const int j = t & 63;
    const int r = t >> 6;
    const int chunk = (npg + NSPLIT - 1) / NSPLIT;
    const int n0 = s * chunk;
    const int n1 = min(npg, n0 + chunk);
    const size_t base = (size_t)g * npg * D_FEAT;

    float sum = 0.f, sq = 0.f;
    for (int n = n0 + r; n < n1; n += 4) {
        float v = io[base + (size_t)n * D_FEAT + j];
        sum += v; sq += v * v;
    }
    __shared__ float s_red[2][4][64];
    s_red[0][r][j] = sum;
    s_red[1][r][j] = sq;
    __syncthreads();
    if (r == 0) {
        float S = s_red[0][0][j] + s_red[0][1][j] + s_red[0][2][j] + s_red[0][3][j];
        float Q = s_red[1][0][j] + s_red[1][1][j] + s_red[1][2][j] + s_red[1][3][j];
        part[(size_t)blockIdx.x * 128 + j]      = S;
        part[(size_t)blockIdx.x * 128 + 64 + j] = Q;
    }
}

__global__ __launch_bounds__(64) void norm_fin_kernel(
    const float* __restrict__ part, float* __restrict__ musc,
    const float* __restrict__ gamma, int npg)
{
    const int g = blockIdx.x;
    const int j = threadIdx.x;
    float S = 0.f, Q = 0.f;
    #pragma unroll
    for (int s = 0; s < NSPLIT; ++s) {
        S += part[(size_t)(g * NSPLIT + s) * 128 + j];
        Q += part[(size_t)(g * NSPLIT + s) * 128 + 64 + j];
    }
    float cnt = (float)npg;
    float mu = S / cnt;
    float var = (Q - cnt * mu * mu) / fmaxf(cnt - 1.f, 1.f);
    var = fmaxf(var, 0.f);
    musc[g * 128 + j]      = mu;
    musc[g * 128 + 64 + j] = gamma[j] / (sqrtf(var) + EPS_N);
}

__global__ __launch_bounds__(256) void norm_apply_kernel(
    float* __restrict__ io, const float* __restrict__ musc,
    const float* __restrict__ beta, int n_nodes, int npg)
{
    const int nf4 = n_nodes * 16;   // float4 count
    for (int i4 = blockIdx.x * blockDim.x + threadIdx.x; i4 < nf4;
         i4 += gridDim.x * blockDim.x) {
        int node = i4 >> 4;
        int j0 = (i4 & 15) * 4;
        int g = node / npg;
        float4 v  = *reinterpret_cast<float4*>(io + (size_t)i4 * 4);
        float4 mu = *reinterpret_cast<const float4*>(musc + g * 128 + j0);
        float4 sc = *reinterpret_cast<const float4*>(musc + g * 128 + 64 + j0);
        float4 be = *reinterpret_cast<const float4*>(beta + j0);
        v.x = (v.x - mu.x) * sc.x + be.x;
        v.y = (v.y - mu.y) * sc.y + be.y;
        v.z = (v.z - mu.z) * sc.z + be.z;
        v.w = (v.w - mu.w) * sc.w + be.w;
        *reinterpret_cast<float4*>(io + (size_t)i4 * 4) = v;
    }
}

extern "C" void kernel_launch(void* const* d_in, const int* in_sizes, int n_in,
                              void* d_out, int out_size, void* d_ws, size_t ws_size,
                              hipStream_t stream)
{
    const float* x      = (const float*)d_in[0];
    const float* states = (const float*)d_in[1];
    const int*   eidx   = (const int*)d_in[2];
    const float* w      = (const float*)d_in[3];
    const float* Ws     = (const float*)d_in[6];
    const float* W1     = (const float*)d_in[7];
    const float* W2     = (const float*)d_in[8];
    const float* gamma  = (const float*)d_in[9];
    const float* beta   = (const float*)d_in[10];

    const int n_nodes  = in_sizes[0] / D_FEAT;
    const int n_edges  = in_sizes[3];
    const int n_graphs = in_sizes[5];
    const int npg      = n_nodes / n_graphs;

    const int nb  = (n_nodes + BUCKET_NODES - 1) / BUCKET_NODES;  // 391
    const int nch = (n_edges + CHUNK_E - 1) / CHUNK_E;            // 293
    const int nscan = nb * nch;

    // workspace layout: h(bf16) | rec | rec2 | bh | partials | row_start
    char* ws = (char*)d_ws;
    size_t hBytes    = ((size_t)n_nodes * D_FEAT * sizeof(unsigned short) + 15) & ~15ULL;
    size_t recBytes  = (size_t)n_edges * sizeof(int2);
    size_t bhBytes   = (size_t)nscan * sizeof(int);
    size_t partBytes = 256 * sizeof(int);
    size_t rsBytes   = (size_t)(n_nodes + 1) * sizeof(int);
    size_t need = hBytes + 2 * recBytes + bhBytes + partBytes + rsBytes;

    unsigned short* h = (unsigned short*)ws;
    float* agg = (float*)d_out;

    // norm scratch aliases the rec region (rec dead before norm runs)
    float* nrm_part = (float*)(ws + hBytes);
    float* nrm_musc = nrm_part + (size_t)n_graphs * NSPLIT * 128;

    mlp_kernel<<<(n_nodes + 63) / 64, 256, 0, stream>>>(x, states, Ws, W1, W2, h, n_nodes);

    const bool ok = (ws_size >= need) && (nb <= NB_MAX) && (n_nodes < (1 << 20));
    if (ok) {
        int2* rec      = (int2*)(ws + hBytes);
        int2* rec2     = (int2*)(ws + hBytes + recBytes);
        int*  bh       = (int*)(ws + hBytes + 2 * recBytes);
        int*  partials = (int*)(ws + hBytes + 2 * recBytes + bhBytes);
        int*  row_start= (int*)(ws + hBytes + 2 * recBytes + bhBytes + partBytes);

        binhist_kernel<<<nch, 256, 0, stream>>>(eidx, bh, n_edges, nb, nch);

        int nchunks = (nscan + SCAN_CHUNK - 1) / SCAN_CHUNK;
        scan1_kernel<<<nchunks, 256, 0, stream>>>(bh, bh, partials, nscan);  // in-place
        scan2_kernel<<<1, 256, 0, stream>>>(partials, nchunks);

        binscatter_kernel<<<nch, 256, 0, stream>>>(eidx, w, bh, partials, rec,
                                                   n_edges, nb, nch);

        bucket_sort_kernel<<<nb, 256, 0, stream>>>(bh, partials, rec, rec2, row_start,
                                                   n_edges, nb, nch, n_nodes);

        node_gather_kernel<<<(n_nodes + 15) / 16, 256, 0, stream>>>(row_start, rec2, h,
                                                                    agg, n_nodes);
    } else {
        hipMemsetAsync(agg, 0, (size_t)n_nodes * D_FEAT * sizeof(float), stream);
        long long sthreads = (long long)n_edges * 16;
        int sblocks = (int)((sthreads + 255) / 256);
        scatter_atomic_kernel<<<sblocks, 256, 0, stream>>>(eidx, w, h, agg, n_edges);
    }

    norm_part_kernel<<<n_graphs * NSPLIT, 256, 0, stream>>>(agg, nrm_part, npg);
    norm_fin_kernel<<<n_graphs, 64, 0, stream>>>(nrm_part, nrm_musc, gamma, npg);
    norm_apply_kernel<<<1024, 256, 0, stream>>>(agg, nrm_musc, beta, n_nodes, npg);
}

// Round 20
// 108.099 us; speedup vs baseline: 2.5556x; 1.0297x over previous
//
#include <hip/hip_runtime.h>
#include <hip/hip_fp16.h>

#define D_FEAT 64
constexpr float SLOPE = 0.01f;
constexpr float EPS_N = 1e-6f;
constexpr int SCAN_CHUNK = 2048;   // elements per scan block (256 thr x 8)
constexpr int CHUNK_E = 4096;      // edges per binning block
constexpr int BUCKET_SHIFT = 8;    // 256 nodes per bucket
constexpr int BUCKET_NODES = 256;
constexpr int NB_MAX = 512;        // max buckets supported by LDS hist
constexpr int NSPLIT = 8;          // blocks per graph for norm partial reduce
constexpr int AP = 72;             // act/wmat LDS pitch in bf16 elems

__device__ __forceinline__ float lrelu(float v) { return v >= 0.f ? v : SLOPE * v; }

// bf16 round-to-nearest-even
__device__ __forceinline__ unsigned short f2bf(float f) {
    union { float f; unsigned u; } v; v.f = f;
    unsigned r = v.u + 0x7FFF + ((v.u >> 16) & 1);
    return (unsigned short)(r >> 16);
}
__device__ __forceinline__ float bf2f(unsigned short b) {
    union { unsigned u; float f; } v; v.u = (unsigned)b << 16;
    return v.f;
}
__device__ __forceinline__ float bflo(unsigned u) {
    union { unsigned u; float f; } v; v.u = u << 16; return v.f;
}
__device__ __forceinline__ float bfhi(unsigned u) {
    union { unsigned u; float f; } v; v.u = u & 0xFFFF0000u; return v.f;
}

typedef short bf16x8 __attribute__((ext_vector_type(8)));
typedef float f32x4  __attribute__((ext_vector_type(4)));

// ---------------------------------------------------------------------------
// MFMA MLP (R17, verified): h = lrelu-chain MLP, h stored bf16.
// Block = 64 nodes x 64 ch, 4 waves; act LDS tile wave-private.
// ---------------------------------------------------------------------------
__global__ __launch_bounds__(256, 4) void mlp_kernel(
    const float* __restrict__ x, const float* __restrict__ states,
    const float* __restrict__ Ws, const float* __restrict__ W1,
    const float* __restrict__ W2, unsigned short* __restrict__ h, int n_nodes)
{
    __shared__ __align__(16) unsigned short act[64 * AP];    // 9216 B
    __shared__ __align__(16) unsigned short wmat[64 * AP];   // 9216 B

    const int t    = threadIdx.x;
    const int lane = t & 63;
    const int wv   = t >> 6;
    const int fr   = lane & 15;
    const int fq   = lane >> 4;
    const int nbase = blockIdx.x * 64;

#define STAGE_WMAT(Wp)                                                        \
    {                                                                         \
        const int row = t >> 2, seg = t & 3;                                  \
        const float* p = (Wp) + row * 64 + seg * 16;                          \
        unsigned short* d = wmat + row * AP + seg * 16;                       \
        _Pragma("unroll")                                                     \
        for (int q = 0; q < 4; ++q) {                                         \
            float4 v = reinterpret_cast<const float4*>(p)[q];                 \
            d[q * 4 + 0] = f2bf(v.x); d[q * 4 + 1] = f2bf(v.y);               \
            d[q * 4 + 2] = f2bf(v.z); d[q * 4 + 3] = f2bf(v.w);               \
        }                                                                     \
    }

    {
        const int row = t >> 2, seg = t & 3;
        const int node = nbase + row;
        float4 v[4];
        if (node < n_nodes) {
            const float* p = states + (size_t)node * 64 + seg * 16;
            #pragma unroll
            for (int q = 0; q < 4; ++q) v[q] = reinterpret_cast<const float4*>(p)[q];
        } else {
            #pragma unroll
            for (int q = 0; q < 4; ++q) v[q] = make_float4(0.f, 0.f, 0.f, 0.f);
        }
        unsigned short* d = act + row * AP + seg * 16;
        #pragma unroll
        for (int q = 0; q < 4; ++q) {
            d[q * 4 + 0] = f2bf(v[q].x); d[q * 4 + 1] = f2bf(v[q].y);
            d[q * 4 + 2] = f2bf(v[q].z); d[q * 4 + 3] = f2bf(v[q].w);
        }
    }
    STAGE_WMAT(Ws);
    __syncthreads();

    f32x4 acc[4];
    const unsigned short* aptr = act + (16 * wv + fr) * AP + fq * 8;

#define MFMA_STAGE()                                                          \
    _Pragma("unroll")                                                         \
    for (int kk = 0; kk < 2; ++kk) {                                          \
        bf16x8 a = *reinterpret_cast<const bf16x8*>(aptr + kk * 32);          \
        _Pragma("unroll")                                                     \
        for (int ct = 0; ct < 4; ++ct) {                                      \
            bf16x8 b = *reinterpret_cast<const bf16x8*>(                      \
                wmat + (16 * ct + fr) * AP + kk * 32 + fq * 8);               \
            acc[ct] = __builtin_amdgcn_mfma_f32_16x16x32_bf16(a, b, acc[ct], 0, 0, 0); \
        }                                                                     \
    }

#define WRITEBACK_LRELU()                                                     \
    _Pragma("unroll")                                                         \
    for (int ct = 0; ct < 4; ++ct)                                            \
        _Pragma("unroll")                                                     \
        for (int r = 0; r < 4; ++r)                                           \
            act[(16 * wv + 4 * fq + r) * AP + 16 * ct + fr] = f2bf(lrelu(acc[ct][r]));

    #pragma unroll
    for (int ct = 0; ct < 4; ++ct) {
        #pragma unroll
        for (int r = 0; r < 4; ++r) {
            int node = nbase + 16 * wv + 4 * fq + r;
            acc[ct][r] = (node < n_nodes) ? x[(size_t)node * 64 + 16 * ct + fr] : 0.f;
        }
    }
    MFMA_STAGE();
    WRITEBACK_LRELU();
    __syncthreads();
    STAGE_WMAT(W1);
    __syncthreads();

    #pragma unroll
    for (int ct = 0; ct < 4; ++ct) acc[ct] = (f32x4){0.f, 0.f, 0.f, 0.f};
    MFMA_STAGE();
    WRITEBACK_LRELU();
    __syncthreads();
    STAGE_WMAT(W2);
    __syncthreads();

    #pragma unroll
    for (int ct = 0; ct < 4; ++ct) acc[ct] = (f32x4){0.f, 0.f, 0.f, 0.f};
    MFMA_STAGE();
    #pragma unroll
    for (int ct = 0; ct < 4; ++ct)
        #pragma unroll
        for (int r = 0; r < 4; ++r)
            act[(16 * wv + 4 * fq + r) * AP + 16 * ct + fr] = f2bf(acc[ct][r]);

    {
        const int row = t >> 2, seg = t & 3;
        const int node = nbase + row;
        if (node < n_nodes) {
            const uint4* s = reinterpret_cast<const uint4*>(act + row * AP + seg * 16);
            uint4* d = reinterpret_cast<uint4*>(h + (size_t)node * 64 + seg * 16);
            d[0] = s[0];
            d[1] = s[1];
        }
    }
#undef STAGE_WMAT
#undef MFMA_STAGE
#undef WRITEBACK_LRELU
}

// ---------------------------------------------------------------------------
// Pass A: per-chunk bucket histogram (bucket = dst >> BUCKET_SHIFT).
// ---------------------------------------------------------------------------
__global__ __launch_bounds__(256) void binhist_kernel(
    const int* __restrict__ eidx, int* __restrict__ bh,
    int n_edges, int nb, int nch)
{
    __shared__ int hist[NB_MAX];
    const int c = blockIdx.x, t = threadIdx.x;
    for (int i = t; i < nb; i += 256) hist[i] = 0;
    __syncthreads();
    const int base = c * CHUNK_E;
    #pragma unroll 4
    for (int k = 0; k < CHUNK_E / 256; ++k) {
        int e = base + k * 256 + t;
        if (e < n_edges) atomicAdd(&hist[eidx[e] >> BUCKET_SHIFT], 1);
    }
    __syncthreads();
    for (int i = t; i < nb; i += 256) bh[i * nch + c] = hist[i];
}

// ---------------------------------------------------------------------------
// Scan: local exclusive per 2048-chunk (scan1) + partials scan (scan2).
// ---------------------------------------------------------------------------
__global__ __launch_bounds__(256) void scan1_kernel(
    const int* __restrict__ in, int* __restrict__ out,
    int* __restrict__ partials, int n)
{
    __shared__ int s[256];
    const int b = blockIdx.x, t = threadIdx.x;
    const int base = b * SCAN_CHUNK + t * 8;
    int v[8]; int sum = 0;
    #pragma unroll
    for (int i = 0; i < 8; ++i) {
        v[i] = (base + i < n) ? in[base + i] : 0;
        sum += v[i];
    }
    s[t] = sum;
    __syncthreads();
    for (int off = 1; off < 256; off <<= 1) {
        int y = (t >= off) ? s[t - off] : 0;
        __syncthreads();
        s[t] += y;
        __syncthreads();
    }
    int excl = s[t] - sum;
    #pragma unroll
    for (int i = 0; i < 8; ++i) {
        if (base + i < n) out[base + i] = excl;
        excl += v[i];
    }
    if (t == 255) partials[b] = s[255];
}

__global__ __launch_bounds__(256) void scan2_kernel(int* partials, int nchunks)
{
    __shared__ int s[256];
    const int t = threadIdx.x;
    int v = (t < nchunks) ? partials[t] : 0;
    s[t] = v;
    __syncthreads();
    for (int off = 1; off < 256; off <<= 1) {
        int y = (t >= off) ? s[t - off] : 0;
        __syncthreads();
        s[t] += y;
        __syncthreads();
    }
    if (t < nchunks) partials[t] = s[t] - v;      // exclusive
}

// ---------------------------------------------------------------------------
// Pass B: binned scatter into per-(bucket,chunk) contiguous runs.
// rec.x = (dstLocal << 20) | src,  rec.y = w bits (f32).
// ---------------------------------------------------------------------------
__global__ __launch_bounds__(256) void binscatter_kernel(
    const int* __restrict__ eidx, const float* __restrict__ w,
    const int* __restrict__ bh, const int* __restrict__ partials,
    int2* __restrict__ rec, int n_edges, int nb, int nch)
{
    __shared__ int cur[NB_MAX];
    const int c = blockIdx.x, t = threadIdx.x;
    for (int i = t; i < nb; i += 256) {
        int idx = i * nch + c;
        cur[i] = bh[idx] + partials[idx / SCAN_CHUNK];
    }
    __syncthreads();
    const int base = c * CHUNK_E;
    #pragma unroll 4
    for (int k = 0; k < CHUNK_E / 256; ++k) {
        int e = base + k * 256 + t;
        if (e < n_edges) {
            int dst = eidx[e];
            int src = eidx[n_edges + e];
            float wv = w[e];
            int b = dst >> BUCKET_SHIFT;
            int dl = dst & (BUCKET_NODES - 1);
            int pos = atomicAdd(&cur[b], 1);
            rec[pos] = make_int2((dl << 20) | src, __float_as_int(wv));
        }
    }
}

// ---------------------------------------------------------------------------
// Pass B2: per-bucket counting sort into per-NODE order + row_start build.
// rec2 COMPRESSED to 4B: low 17 bits = src (n_nodes < 2^17), high 15 bits =
// fp16 bits of w (sign always 0 since w >= 0). fp16 rel err 2^-11.
// ---------------------------------------------------------------------------
__global__ __launch_bounds__(256) void bucket_sort_kernel(
    const int* __restrict__ bh, const int* __restrict__ partials,
    const int2* __restrict__ rec, unsigned* __restrict__ rec2,
    int* __restrict__ row_start, int n_edges, int nb, int nch, int n_nodes)
{
    __shared__ int cnt[BUCKET_NODES];
    __shared__ int s[BUCKET_NODES];
    __shared__ int pos[BUCKET_NODES];

    const int b = blockIdx.x, t = threadIdx.x;
    const int iS = b * nch;
    const int S = bh[iS] + partials[iS / SCAN_CHUNK];
    int E = n_edges;
    if (b + 1 < nb) {
        int iE = (b + 1) * nch;
        E = bh[iE] + partials[iE / SCAN_CHUNK];
    }

    cnt[t] = 0;
    __syncthreads();
    for (int i = S + t; i < E; i += 256)
        atomicAdd(&cnt[rec[i].x >> 20], 1);
    __syncthreads();

    int my = cnt[t];
    s[t] = my;
    __syncthreads();
    for (int off = 1; off < 256; off <<= 1) {
        int y = (t >= off) ? s[t - off] : 0;
        __syncthreads();
        s[t] += y;
        __syncthreads();
    }
    int excl = s[t] - my;
    pos[t] = S + excl;
    const int node = (b << BUCKET_SHIFT) + t;
    if (node < n_nodes) row_start[node] = S + excl;
    if (b == nb - 1 && t == 0) row_start[n_nodes] = n_edges;
    __syncthreads();

    for (int i = S + t; i < E; i += 256) {
        int2 r = rec[i];
        int p = atomicAdd(&pos[r.x >> 20], 1);
        unsigned src = (unsigned)(r.x & 0xFFFFF);
        unsigned short hb = __half_as_ushort(__float2half(__int_as_float(r.y)));
        rec2[p] = src | ((unsigned)hb << 17);
    }
}

// ---------------------------------------------------------------------------
// Pass C: atomic-free gather, 8 NODES PER WAVE (8-lane groups).
// Lane = 8 channels via one 16B uint4 load (b128); group covers the full
// 128B h row coalesced. 8 independent edge streams/wave x ILP-4 = 32
// outstanding loads. rec2 is 4B compressed (src | fp16w<<17).
// ---------------------------------------------------------------------------
__global__ __launch_bounds__(256, 8) void node_gather_kernel(
    const int* __restrict__ row_start, const unsigned* __restrict__ rec2,
    const unsigned short* __restrict__ h, float* __restrict__ agg, int n_nodes)
{
    const int wv   = threadIdx.x >> 6;
    const int lane = threadIdx.x & 63;
    const int sub  = lane >> 3;          // node slot within wave (0..7)
    const int ll   = lane & 7;           // channel oct: ch 8*ll .. 8*ll+7
    const int node = blockIdx.x * 32 + wv * 8 + sub;
    if (node >= n_nodes) return;

    const int start = row_start[node];
    const int end   = row_start[node + 1];

    float a0 = 0.f, a1 = 0.f, a2 = 0.f, a3 = 0.f;
    float a4 = 0.f, a5 = 0.f, a6 = 0.f, a7 = 0.f;
    int i = start;

#define EDGE_ACC(rr, qq)                                                      \
    {                                                                         \
        float wt = __half2float(__ushort_as_half((unsigned short)((rr) >> 17))); \
        a0 += wt * bflo(qq.x); a1 += wt * bfhi(qq.x);                         \
        a2 += wt * bflo(qq.y); a3 += wt * bfhi(qq.y);                         \
        a4 += wt * bflo(qq.z); a5 += wt * bfhi(qq.z);                         \
        a6 += wt * bflo(qq.w); a7 += wt * bfhi(qq.w);                         \
    }

    for (; i + 4 <= end; i += 4) {
        unsigned r[4];
        #pragma unroll
        for (int k = 0; k < 4; ++k) r[k] = rec2[i + k];      // 4 independent
        uint4 q[4];
        #pragma unroll
        for (int k = 0; k < 4; ++k)                          // 4 independent b128
            q[k] = *reinterpret_cast<const uint4*>(
                h + (size_t)(r[k] & 0x1FFFF) * D_FEAT + ll * 8);
        #pragma unroll
        for (int k = 0; k < 4; ++k) EDGE_ACC(r[k], q[k]);
    }
    for (; i < end; ++i) {
        unsigned r = rec2[i];
        uint4 q = *reinterpret_cast<const uint4*>(
            h + (size_t)(r & 0x1FFFF) * D_FEAT + ll * 8);
        EDGE_ACC(r, q);
    }
#undef EDGE_ACC

    float4 o0 = make_float4(a0, a1, a2, a3);
    float4 o1 = make_float4(a4, a5, a6, a7);
    float* dst = agg + (size_t)node * D_FEAT + ll * 8;
    *reinterpret_cast<float4*>(dst)     = o0;
    *reinterpret_cast<float4*>(dst + 4) = o1;
}

// ---------------------------------------------------------------------------
// Fallback scatter (atomics) if workspace too small / shape unsupported
// ---------------------------------------------------------------------------
__global__ __launch_bounds__(256) void scatter_atomic_kernel(
    const int* __restrict__ eidx, const float* __restrict__ w,
    const unsigned short* __restrict__ h, float* __restrict__ agg, int n_edges)
{
    long long t = (long long)blockIdx.x * blockDim.x + threadIdx.x;
    int e = (int)(t >> 4);
    if (e >= n_edges) return;
    int c = ((int)t & 15) * 4;
    int dst = eidx[e];
    int src = eidx[n_edges + e];
    float wv = w[e];
    const unsigned short* hp = h + (size_t)src * D_FEAT + c;
    float* p = agg + (size_t)dst * D_FEAT + c;
    unsafeAtomicAdd(p + 0, wv * bf2f(hp[0]));
    unsafeAtomicAdd(p + 1, wv * bf2f(hp[1]));
    unsafeAtomicAdd(p + 2, wv * bf2f(hp[2]));
    unsafeAtomicAdd(p + 3, wv * bf2f(hp[3]));
}

// ---------------------------------------------------------------------------
// GraphNorm, parallelized: partial reduce -> finalize -> apply.
// ---------------------------------------------------------------------------
__global__ __launch_bounds__(256) void norm_part_kernel(
    const float* __restrict__ io, float* __restrict__ part, int npg)
{
    const int g = blockIdx.x / NSPLIT;
    const int s = blockIdx.x % NSPLIT;
    const int t = threadIdx.x;
    const int j = t & 63;
    const int r = t >> 6;
    const int chunk = (npg + NSPLIT - 1) / NSPLIT;
    const int n0 = s * chunk;
    const int n1 = min(npg, n0 + chunk);
    const size_t base = (size_t)g * npg * D_FEAT;

    float sum = 0.f, sq = 0.f;
    for (int n = n0 + r; n < n1; n += 4) {
        float v = io[base + (size_t)n * D_FEAT + j];
        sum += v; sq += v * v;
    }
    __shared__ float s_red[2][4][64];
    s_red[0][r][j] = sum;
    s_red[1][r][j] = sq;
    __syncthreads();
    if (r == 0) {
        float S = s_red[0][0][j] + s_red[0][1][j] + s_red[0][2][j] + s_red[0][3][j];
        float Q = s_red[1][0][j] + s_red[1][1][j] + s_red[1][2][j] + s_red[1][3][j];
        part[(size_t)blockIdx.x * 128 + j]      = S;
        part[(size_t)blockIdx.x * 128 + 64 + j] = Q;
    }
}

__global__ __launch_bounds__(64) void norm_fin_kernel(
    const float* __restrict__ part, float* __restrict__ musc,
    const float* __restrict__ gamma, int npg)
{
    const int g = blockIdx.x;
    const int j = threadIdx.x;
    float S = 0.f, Q = 0.f;
    #pragma unroll
    for (int s = 0; s < NSPLIT; ++s) {
        S += part[(size_t)(g * NSPLIT + s) * 128 + j];
        Q += part[(size_t)(g * NSPLIT + s) * 128 + 64 + j];
    }
    float cnt = (float)npg;
    float mu = S / cnt;
    float var = (Q - cnt * mu * mu) / fmaxf(cnt - 1.f, 1.f);
    var = fmaxf(var, 0.f);
    musc[g * 128 + j]      = mu;
    musc[g * 128 + 64 + j] = gamma[j] / (sqrtf(var) + EPS_N);
}

__global__ __launch_bounds__(256) void norm_apply_kernel(
    float* __restrict__ io, const float* __restrict__ musc,
    const float* __restrict__ beta, int n_nodes, int npg)
{
    const int nf4 = n_nodes * 16;   // float4 count
    for (int i4 = blockIdx.x * blockDim.x + threadIdx.x; i4 < nf4;
         i4 += gridDim.x * blockDim.x) {
        int node = i4 >> 4;
        int j0 = (i4 & 15) * 4;
        int g = node / npg;
        float4 v  = *reinterpret_cast<float4*>(io + (size_t)i4 * 4);
        float4 mu = *reinterpret_cast<const float4*>(musc + g * 128 + j0);
        float4 sc = *reinterpret_cast<const float4*>(musc + g * 128 + 64 + j0);
        float4 be = *reinterpret_cast<const float4*>(beta + j0);
        v.x = (v.x - mu.x) * sc.x + be.x;
        v.y = (v.y - mu.y) * sc.y + be.y;
        v.z = (v.z - mu.z) * sc.z + be.z;
        v.w = (v.w - mu.w) * sc.w + be.w;
        *reinterpret_cast<float4*>(io + (size_t)i4 * 4) = v;
    }
}

extern "C" void kernel_launch(void* const* d_in, const int* in_sizes, int n_in,
                              void* d_out, int out_size, void* d_ws, size_t ws_size,
                              hipStream_t stream)
{
    const float* x      = (const float*)d_in[0];
    const float* states = (const float*)d_in[1];
    const int*   eidx   = (const int*)d_in[2];
    const float* w      = (const float*)d_in[3];
    const float* Ws     = (const float*)d_in[6];
    const float* W1     = (const float*)d_in[7];
    const float* W2     = (const float*)d_in[8];
    const float* gamma  = (const float*)d_in[9];
    const float* beta   = (const float*)d_in[10];

    const int n_nodes  = in_sizes[0] / D_FEAT;
    const int n_edges  = in_sizes[3];
    const int n_graphs = in_sizes[5];
    const int npg      = n_nodes / n_graphs;

    const int nb  = (n_nodes + BUCKET_NODES - 1) / BUCKET_NODES;  // 391
    const int nch = (n_edges + CHUNK_E - 1) / CHUNK_E;            // 293
    const int nscan = nb * nch;

    // workspace layout: h(bf16) | rec | rec2 | bh | partials | row_start
    char* ws = (char*)d_ws;
    size_t hBytes    = ((size_t)n_nodes * D_FEAT * sizeof(unsigned short) + 15) & ~15ULL;
    size_t recBytes  = (size_t)n_edges * sizeof(int2);
    size_t rec2Bytes = ((size_t)n_edges * sizeof(unsigned) + 15) & ~15ULL;
    size_t bhBytes   = (size_t)nscan * sizeof(int);
    size_t partBytes = 256 * sizeof(int);
    size_t rsBytes   = (size_t)(n_nodes + 1) * sizeof(int);
    size_t need = hBytes + recBytes + rec2Bytes + bhBytes + partBytes + rsBytes;

    unsigned short* h = (unsigned short*)ws;
    float* agg = (float*)d_out;

    // norm scratch aliases the rec region (rec dead before norm runs)
    float* nrm_part = (float*)(ws + hBytes);
    float* nrm_musc = nrm_part + (size_t)n_graphs * NSPLIT * 128;

    mlp_kernel<<<(n_nodes + 63) / 64, 256, 0, stream>>>(x, states, Ws, W1, W2, h, n_nodes);

    const bool ok = (ws_size >= need) && (nb <= NB_MAX) && (n_nodes < (1 << 17));
    if (ok) {
        int2*     rec      = (int2*)(ws + hBytes);
        unsigned* rec2     = (unsigned*)(ws + hBytes + recBytes);
        int*      bh       = (int*)(ws + hBytes + recBytes + rec2Bytes);
        int*      partials = (int*)(ws + hBytes + recBytes + rec2Bytes + bhBytes);
        int*      row_start= (int*)(ws + hBytes + recBytes + rec2Bytes + bhBytes + partBytes);

        binhist_kernel<<<nch, 256, 0, stream>>>(eidx, bh, n_edges, nb, nch);

        int nchunks = (nscan + SCAN_CHUNK - 1) / SCAN_CHUNK;
        scan1_kernel<<<nchunks, 256, 0, stream>>>(bh, bh, partials, nscan);  // in-place
        scan2_kernel<<<1, 256, 0, stream>>>(partials, nchunks);

        binscatter_kernel<<<nch, 256, 0, stream>>>(eidx, w, bh, partials, rec,
                                                   n_edges, nb, nch);

        bucket_sort_kernel<<<nb, 256, 0, stream>>>(bh, partials, rec, rec2, row_start,
                                                   n_edges, nb, nch, n_nodes);

        node_gather_kernel<<<(n_nodes + 31) / 32, 256, 0, stream>>>(row_start, rec2, h,
                                                                    agg, n_nodes);
    } else {
        hipMemsetAsync(agg, 0, (size_t)n_nodes * D_FEAT * sizeof(float), stream);
        long long sthreads = (long long)n_edges * 16;
        int sblocks = (int)((sthreads + 255) / 256);
        scatter_atomic_kernel<<<sblocks, 256, 0, stream>>>(eidx, w, h, agg, n_edges);
    }

    norm_part_kernel<<<n_graphs * NSPLIT, 256, 0, stream>>>(agg, nrm_part, npg);
    norm_fin_kernel<<<n_graphs, 64, 0, stream>>>(nrm_part, nrm_musc, gamma, npg);
    norm_apply_kernel<<<1024, 256, 0, stream>>>(agg, nrm_musc, beta, n_nodes, npg);
}